// Round 5
// baseline (297.130 us; speedup 1.0000x reference)
//
#include <hip/hip_runtime.h>
#include <stdint.h>

#define NNODES 20000
#define NEDGES 400000
#define MTILES 1250   // 20000/16
#define MT2    625    // 20000/32 (k_l1: 2 mtiles per block)
#define KS1 68        // layer-1 msg GEMM ksteps: 64 (T@V1) + 4 (zi@Ws1)

typedef __attribute__((ext_vector_type(8))) short short8;
typedef __attribute__((ext_vector_type(4))) float floatx4;

__device__ __forceinline__ float bf2f(uint16_t u){ return __uint_as_float(((uint32_t)u)<<16); }
__device__ __forceinline__ uint16_t f2bf(float f){
  uint32_t x = __float_as_uint(f);
  x += 0x7FFFu + ((x>>16)&1u);
  return (uint16_t)(x>>16);
}
__device__ __forceinline__ uint32_t packbf(float a, float b){
  return (uint32_t)f2bf(a) | ((uint32_t)f2bf(b)<<16);
}
__device__ __forceinline__ float siluf(float x){ return x/(1.0f+__expf(-x)); }
__device__ __forceinline__ float ldf(const void* p, int i, int md){
  return (md==1) ? bf2f(((const uint16_t*)p)[i]) : ((const float*)p)[i];
}

// converted-weights layout (float elements within conv buffer)
#define OFF_V0   0
#define N_V0     32768
#define OFF_WS1  32768
#define N_WS1    16384
#define OFF_BS1  49152
#define N_BS1    128
#define OFF_V1   49280
#define N_V1     262144
#define OFF_WA   311424
#define N_WA     98304
#define OFF_BA   409728
#define N_BA     768
#define OFF_WB   410496
#define N_WB     98304
#define OFF_BB   508800
#define N_BB     768
#define N_CONV   509568

// ---------------- dtype probe ----------------
__global__ void k_probe(const void* dist, int* mode){
  if(threadIdx.x != 0 || blockIdx.x != 0) return;
  const float* f = (const float*)dist;
  const uint16_t* h = (const uint16_t*)dist;
  int okf = 1, okb = 1;
  for(int i=0;i<256;i++){
    float a = f[i];       okf &= (a >= 0.7f) & (a <= 5.1f);
    float b = bf2f(h[i]); okb &= (b >= 0.7f) & (b <= 5.1f);
  }
  *mode = okb ? 1 : (okf ? 0 : 1);
}

// ---------------- convert all weight tensors to fp32 ----------------
__global__ __launch_bounds__(256) void k_conv(const void* s0,const void* s1,const void* s2,const void* s3,
                                              const void* s4,const void* s5,const void* s6,const void* s7,
                                              const int* __restrict__ modep, float* __restrict__ dst){
  int md = *modep;
  int i = blockIdx.x*256 + threadIdx.x;
  if(i >= N_CONV) return;
  const void* src; int t = i;
  if(t < N_V0){src=s0;}
  else if((t-=N_V0) < N_WS1){src=s1;}
  else if((t-=N_WS1) < N_BS1){src=s2;}
  else if((t-=N_BS1) < N_V1){src=s3;}
  else if((t-=N_V1) < N_WA){src=s4;}
  else if((t-=N_WA) < N_BA){src=s5;}
  else if((t-=N_BA) < N_WB){src=s6;}
  else {t-=N_WB; src=s7;}
  dst[i] = ldf(src, t, md);
}

// ---------------- CSR build ----------------
__global__ __launch_bounds__(256) void k_hist(const int* __restrict__ src, int* __restrict__ cnt){
  int e = blockIdx.x*256 + threadIdx.x;
  if(e < NEDGES){
    int s = src[e];
    if((unsigned)s < NNODES) atomicAdd(&cnt[s], 1);
  }
}

// parallel scan: 1024 threads, chunk=20/thread; wave shuffle-scan + LDS cross-wave scan
__global__ __launch_bounds__(1024) void k_scan(int* cnt_cur, int* offs){
  __shared__ int wsum[16];
  int t = threadIdx.x;
  const int chunk = (NNODES + 1023)/1024;   // 20
  int lo = t*chunk, hi = lo+chunk;
  if(lo > NNODES) lo = NNODES;
  if(hi > NNODES) hi = NNODES;
  int s = 0;
  for(int i=lo;i<hi;i++) s += cnt_cur[i];
  int lane = t&63, wv = t>>6;
  int v = s;
  #pragma unroll
  for(int d=1; d<64; d<<=1){
    int u = __shfl_up(v, d);
    if(lane >= d) v += u;
  }
  if(lane==63) wsum[wv] = v;
  __syncthreads();
  if(t==0){
    int run = 0;
    #pragma unroll
    for(int i=0;i<16;i++){ int c = wsum[i]; wsum[i] = run; run += c; }
  }
  __syncthreads();
  int run = wsum[wv] + (v - s);   // exclusive prefix of this thread's chunk
  for(int i=lo;i<hi;i++){
    int c = cnt_cur[i];
    offs[i] = run;
    cnt_cur[i] = run;
    run += c;
  }
  if(t==1023) offs[NNODES] = run;  // thread 1023's chunk is empty -> run == total == NEDGES
}

// ---------------- fused CSR-fill + radial basis (k_fill + k_G) ----------------
// per edge: slot p via atomicAdd, write dsts/sps, compute G row and write gs[p]
// directly -- removes the pos array (3.2 MB round trip) and one 400k-thread launch.
__global__ __launch_bounds__(256) void k_fillG(const int* __restrict__ src,
                                               const int* __restrict__ edst,
                                               const int* __restrict__ species,
                                               int* __restrict__ cur,
                                               const void* __restrict__ dist,
                                               const void* __restrict__ sw,
                                               const int* __restrict__ modep,
                                               int* __restrict__ dsts,
                                               int* __restrict__ sps,
                                               uint16_t* __restrict__ gs){
  int e = blockIdx.x*256 + threadIdx.x;
  if(e >= NEDGES) return;
  int md = *modep;
  int s = src[e];
  if((unsigned)s >= NNODES) s = 0;
  int p = atomicAdd(&cur[s], 1);
  if((unsigned)p >= NEDGES) p = 0;
  int dn = edst[e];
  if((unsigned)dn >= NNODES) dn = 0;
  dsts[p] = dn;
  int sp = species[dn];
  if((unsigned)sp >= 51) sp = 0;
  sps[p] = sp;
  float r = ldf(dist, e, md);
  float w = ldf(sw, e, md);
  float rinv = 1.0f/r;
  const float sigma = 0.8f/15.0f;
  const float isig  = 15.0f/0.8f;
  uint32_t u[8];
  #pragma unroll
  for(int j=0;j<8;j++){
    float mu0 = 0.2f + sigma*(float)(2*j);
    float mu1 = 0.2f + sigma*(float)(2*j+1);
    float t0 = (rinv-mu0)*isig, t1 = (rinv-mu1)*isig;
    u[j] = packbf(w*__expf(-0.5f*t0*t0), w*__expf(-0.5f*t1*t1));
  }
  uint4* o = (uint4*)(gs + (size_t)p*16);
  o[0] = make_uint4(u[0],u[1],u[2],u[3]);
  o[1] = make_uint4(u[4],u[5],u[6],u[7]);
}

// ---------------- species tables: ZWs0 fp32, zfb bf16 (51x16) ----------------
__global__ __launch_bounds__(128) void k_spec(const void* __restrict__ Z,
                                              const void* __restrict__ Ws0,
                                              const void* __restrict__ bs0,
                                              const int* __restrict__ modep,
                                              float* __restrict__ ZWs0,
                                              uint16_t* __restrict__ zfb){
  int s = blockIdx.x, d = threadIdx.x;
  int md = *modep;
  float zk[16];
  #pragma unroll
  for(int k=0;k<16;k++) zk[k] = ldf(Z, s*16+k, md);
  float a = ldf(bs0, d, md);
  #pragma unroll
  for(int k=0;k<16;k++) a = fmaf(zk[k], ldf(Ws0, k*128+d, md), a);
  ZWs0[s*128+d] = a;
  if(d < 16) zfb[s*16+d] = f2bf(zk[d]);
}

// ---------------- pack W (Kx128 fp32) into MFMA B-fragment layout, bf16 ----------------
__global__ __launch_bounds__(256) void k_prepB(const float* __restrict__ W, int Ksteps,
                                               uint16_t* __restrict__ Bf){
  int idx = blockIdx.x*256 + threadIdx.x;
  int total = Ksteps*8*64;
  if(idx >= total) return;
  int l = idx & 63, nt = (idx>>6)&7, kk = idx>>9;
  int kbase = kk*32 + (l>>4)*8;
  int dim = nt*16 + (l&15);
  uint32_t u[4];
  #pragma unroll
  for(int t=0;t<4;t++){
    float f0 = W[(size_t)(kbase+2*t)*128 + dim];
    float f1 = W[(size_t)(kbase+2*t+1)*128 + dim];
    u[t] = packbf(f0,f1);
  }
  ((uint4*)Bf)[idx] = make_uint4(u[0],u[1],u[2],u[3]);
}

// pack all 12 onsite 128x128 weights into frags
__global__ __launch_bounds__(256) void k_prepW(const float* __restrict__ conv,
                                               uint16_t* __restrict__ Wf){
  int idx = blockIdx.x*256 + threadIdx.x;
  if(idx >= 12*2048) return;
  int wi = idx>>11, r = idx&2047;
  int l = r & 63, nt = (r>>6)&7, kk = r>>9;
  const float* W = conv + ((wi<6) ? (OFF_WA + wi*16384) : (OFF_WB + (wi-6)*16384));
  int kbase = kk*32 + (l>>4)*8;
  int dim = nt*16 + (l&15);
  uint32_t u[4];
  #pragma unroll
  for(int t=0;t<4;t++){
    float f0 = W[(size_t)(kbase+2*t)*128 + dim];
    float f1 = W[(size_t)(kbase+2*t+1)*128 + dim];
    u[t] = packbf(f0,f1);
  }
  ((uint4*)Wf)[idx] = make_uint4(u[0],u[1],u[2],u[3]);
}

// ---------------- layer-0 FUSED: msg (MFMA scatter + GEMM) + onsite, one block = one mtile ----
// R4 fusion: msg epilogue -> LDS zb (was global zi, 20.5 MB round trip); onsite in-block;
// fp32 zi store dropped entirely (nothing downstream reads it -- only zib/zib2/out matter).
__global__ __launch_bounds__(256) void k_l0(const int* __restrict__ offs,
                                            const int* __restrict__ sps,
                                            const uint16_t* __restrict__ gs,
                                            const uint16_t* __restrict__ zfb,
                                            const uint16_t* __restrict__ Bf,
                                            const int* __restrict__ species,
                                            const float* __restrict__ ZWs0,
                                            const uint16_t* __restrict__ Waf,
                                            const float* __restrict__ ba,
                                            const uint16_t* __restrict__ Wbf,
                                            const float* __restrict__ bb,
                                            void* __restrict__ outb,
                                            const int* __restrict__ modep,
                                            uint16_t* __restrict__ zib,
                                            uint16_t* __restrict__ zib2){
  __shared__ uint16_t ldsA[8*64*8];   // 8 KB
  __shared__ float zb[16*132];
  __shared__ float hb[16*132];
  int w = threadIdx.x>>6, l = threadIdx.x&63;
  int n0 = blockIdx.x*16;
  int col = l&15, quad = l>>4;
  // phase A: 4 nodes per wave; T0^T[zk][b] = sum_e zfb[sp_e][zk] * g[e][b]
  for(int i=0;i<4;i++){
    int m = w*4 + i;
    int n = n0 + m;
    int beg = offs[n], end = offs[n+1];
    floatx4 acc0 = (floatx4){0.f,0.f,0.f,0.f};
    for(int p0=beg; p0<end; p0+=32){
      int sp[8];
      union { short8 s; uint16_t u[8]; } Bg, Az;
      #pragma unroll
      for(int j=0;j<8;j++){
        int p = p0 + quad*8 + j;
        int pc = p < end ? p : beg;
        sp[j] = sps[pc];
        uint16_t g = gs[(size_t)pc*16 + col];
        Bg.u[j] = (p < end) ? g : (uint16_t)0;
      }
      #pragma unroll
      for(int j=0;j<8;j++)
        Az.u[j] = zfb[sp[j]*16 + col];
      acc0 = __builtin_amdgcn_mfma_f32_16x16x32_bf16(Az.s, Bg.s, acc0, 0,0,0);
    }
    int K0 = col*16 + quad*4;
    int kk = K0>>5, qt = (K0>>3)&3, jt = K0&7;
    int slot = kk*64 + ((qt*16 + m) ^ (kk>>2));
    uint32_t lo = packbf(acc0[0], acc0[1]);
    uint32_t hi = packbf(acc0[2], acc0[3]);
    *(uint2*)(&ldsA[slot*8 + jt]) = make_uint2(lo, hi);
  }
  __syncthreads();
  // phase B: wave w -> ntiles w and w+4
  floatx4 acc1 = (floatx4){0.f,0.f,0.f,0.f};
  floatx4 acc2 = (floatx4){0.f,0.f,0.f,0.f};
  const short8* Bp = (const short8*)Bf;
  int nt1 = w, nt2 = w+4;
  #pragma unroll
  for(int kk=0;kk<8;kk++){
    short8 a = *(const short8*)(&ldsA[(kk*64 + (l^(kk>>2)))*8]);
    short8 b1 = Bp[(size_t)(kk*8+nt1)*64 + l];
    short8 b2 = Bp[(size_t)(kk*8+nt2)*64 + l];
    acc1 = __builtin_amdgcn_mfma_f32_16x16x32_bf16(a, b1, acc1, 0,0,0);
    acc2 = __builtin_amdgcn_mfma_f32_16x16x32_bf16(a, b2, acc2, 0,0,0);
  }
  // epilogue -> LDS zb (silu(msg + zself))
  #pragma unroll
  for(int reg=0;reg<4;reg++){
    int node = n0 + quad*4 + reg;
    int sp = species[node];
    if((unsigned)sp >= 51) sp = 0;
    int d1 = nt1*16 + col, d2 = nt2*16 + col;
    int row = quad*4 + reg;
    zb[row*132 + d1] = siluf(acc1[reg] + ZWs0[sp*128 + d1]);
    zb[row*132 + d2] = siluf(acc2[reg] + ZWs0[sp*128 + d2]);
  }
  __syncthreads();
  // onsite: 3 x (h = silu(z@Wa+ba); z += h@Wb+bb); wave w -> ntiles 2w, 2w+1
  int m = col, q = quad;
  for(int j=0;j<3;j++){
    const short8* Ba = (const short8*)Waf + (size_t)j*2048 + l;
    floatx4 acc[2];
    acc[0] = (floatx4){0.f,0.f,0.f,0.f};
    acc[1] = (floatx4){0.f,0.f,0.f,0.f};
    #pragma unroll
    for(int kk=0;kk<4;kk++){
      const float* zp = zb + m*132 + kk*32 + q*8;
      float4 a0 = *(const float4*)zp, a1 = *(const float4*)(zp+4);
      union { short8 s; uint32_t u[4]; } A;
      A.u[0]=packbf(a0.x,a0.y); A.u[1]=packbf(a0.z,a0.w);
      A.u[2]=packbf(a1.x,a1.y); A.u[3]=packbf(a1.z,a1.w);
      #pragma unroll
      for(int t=0;t<2;t++){
        short8 bfr = Ba[(size_t)(kk*8 + w*2+t)*64];
        acc[t] = __builtin_amdgcn_mfma_f32_16x16x32_bf16(A.s, bfr, acc[t], 0,0,0);
      }
    }
    #pragma unroll
    for(int t=0;t<2;t++){
      int dim = (w*2+t)*16 + m;
      float bv = ba[j*128+dim];
      #pragma unroll
      for(int reg=0;reg<4;reg++)
        hb[(q*4+reg)*132 + dim] = siluf(acc[t][reg] + bv);
    }
    __syncthreads();
    const short8* Bb = (const short8*)Wbf + (size_t)j*2048 + l;
    floatx4 acc2o[2];
    acc2o[0] = (floatx4){0.f,0.f,0.f,0.f};
    acc2o[1] = (floatx4){0.f,0.f,0.f,0.f};
    #pragma unroll
    for(int kk=0;kk<4;kk++){
      const float* hp = hb + m*132 + kk*32 + q*8;
      float4 a0 = *(const float4*)hp, a1 = *(const float4*)(hp+4);
      union { short8 s; uint32_t u[4]; } A;
      A.u[0]=packbf(a0.x,a0.y); A.u[1]=packbf(a0.z,a0.w);
      A.u[2]=packbf(a1.x,a1.y); A.u[3]=packbf(a1.z,a1.w);
      #pragma unroll
      for(int t=0;t<2;t++){
        short8 bfr = Bb[(size_t)(kk*8 + w*2+t)*64];
        acc2o[t] = __builtin_amdgcn_mfma_f32_16x16x32_bf16(A.s, bfr, acc2o[t], 0,0,0);
      }
    }
    #pragma unroll
    for(int t=0;t<2;t++){
      int dim = (w*2+t)*16 + m;
      float bv = bb[j*128+dim];
      #pragma unroll
      for(int reg=0;reg<4;reg++){
        int idx = (q*4+reg)*132 + dim;
        zb[idx] = zb[idx] + acc2o[t][reg] + bv;
      }
    }
    __syncthreads();
  }
  // final store: out(stack layer0), zib, zib2 (NO fp32 zi)
  int md = *modep;
  const long ZIS = (long)NNODES*128;
  #pragma unroll
  for(int i=0;i<2;i++){
    int flat = (i*256 + threadIdx.x)*4;
    int node = flat>>7, k = flat&127;
    float4 v = *(float4*)(zb + node*132 + k);
    int n = n0 + node;
    uint2 pv = make_uint2(packbf(v.x,v.y), packbf(v.z,v.w));
    *(uint2*)(zib + (size_t)n*128 + k) = pv;
    if(md==1){
      uint16_t* ob = (uint16_t*)outb;
      *(uint2*)(ob + ZIS + (long)n*256 + k) = pv;
    } else {
      float* ob = (float*)outb;
      *(float4*)(ob + ZIS + (long)n*256 + k) = v;
    }
  }
  {
    int node2 = threadIdx.x>>4, c = threadIdx.x&15;
    float vv[8];
    #pragma unroll
    for(int mt=0;mt<8;mt++) vv[mt] = zb[node2*132 + mt*16 + c];
    uint4 o = make_uint4(packbf(vv[0],vv[1]), packbf(vv[2],vv[3]),
                         packbf(vv[4],vv[5]), packbf(vv[6],vv[7]));
    *(uint4*)(zib2 + (size_t)(n0+node2)*128 + c*8) = o;
  }
}

// ---------------- layer-1 FUSED: msg (2 mtiles, split-K) + onsite, block = 16 waves ----------
// R3 structure kept: 2 A-tiles share each Bf fragment (2 MFMAs per b1 load), 128 KB ldsA,
// split-K wave pairs + LDS reduction. R4 adds: epilogue -> LDS zb tiles (carved from the
// dead ldsA region after the reduction), onsite with 8 waves per mtile (1 ntile/wave),
// direct store to d_out. Removes the zacc 20.5 MB round trip + a 1250-block onsite launch
// and halves onsite weight-fragment L2 traffic (625 blocks read Wa/Wb frags, not 1250).
__global__ __launch_bounds__(1024, 2) void k_l1(const int* __restrict__ offs,
                                               const int* __restrict__ dsts,
                                               const uint16_t* __restrict__ gs,
                                               const uint16_t* __restrict__ zib,   // linear, ksteps 64..67
                                               const uint16_t* __restrict__ zib2,  // transposed, gathers
                                               const uint16_t* __restrict__ Bf,
                                               const float* __restrict__ bias,
                                               const uint16_t* __restrict__ Waf,
                                               const float* __restrict__ ba,
                                               const uint16_t* __restrict__ Wbf,
                                               const float* __restrict__ bb,
                                               void* __restrict__ outb,
                                               const int* __restrict__ modep){
  __shared__ __align__(16) uint16_t ldsA[2*64*64*8];   // 128 KB: two 64-KB A-tiles
  int w = threadIdx.x>>6, l = threadIdx.x&63;
  int n0 = blockIdx.x*32;
  int col = l&15, quad = l>>4;
  // phase A: 2 nodes per wave
  for(int i=0;i<2;i++){
    int m = w*2 + i;            // 0..31
    int n = n0 + m;
    int beg = offs[n], end = offs[n+1];
    floatx4 acc[8];
    #pragma unroll
    for(int t=0;t<8;t++) acc[t] = (floatx4){0.f,0.f,0.f,0.f};
    for(int p0=beg; p0<end; p0+=32){
      int dn[8];
      union { short8 s; uint16_t u[8]; } Bg;
      #pragma unroll
      for(int j=0;j<8;j++){
        int p = p0 + quad*8 + j;
        int pc = p < end ? p : beg;
        dn[j] = dsts[pc];
        uint16_t g = gs[(size_t)pc*16 + col];
        Bg.u[j] = (p < end) ? g : (uint16_t)0;
      }
      uint4 row[8];
      #pragma unroll
      for(int j=0;j<8;j++)
        row[j] = *(const uint4*)(zib2 + (size_t)dn[j]*128 + col*8);
      #pragma unroll
      for(int mt=0;mt<8;mt++){
        union { short8 s; uint32_t u32[4]; } Az;
        #pragma unroll
        for(int cp=0;cp<4;cp++){
          uint32_t a = ((const uint32_t*)&row[2*cp])[mt>>1];
          uint32_t b = ((const uint32_t*)&row[2*cp+1])[mt>>1];
          Az.u32[cp] = __builtin_amdgcn_perm(b, a, (mt&1) ? 0x07060302u : 0x05040100u);
        }
        acc[mt] = __builtin_amdgcn_mfma_f32_16x16x32_bf16(Az.s, Bg.s, acc[mt], 0,0,0);
      }
    }
    uint16_t* tile = ldsA + (size_t)(m>>4)*32768;
    int mloc = m & 15;
    #pragma unroll
    for(int mt=0;mt<8;mt++){
      int K0 = col*128 + mt*16 + quad*4;
      int kk = K0>>5, qt = (K0>>3)&3, jt = K0&7;
      int slot = kk*64 + ((qt*16 + mloc) ^ (kk>>2));
      uint32_t lo = packbf(acc[mt][0], acc[mt][1]);
      uint32_t hi = packbf(acc[mt][2], acc[mt][3]);
      *(uint2*)(&tile[slot*8 + jt]) = make_uint2(lo, hi);
    }
  }
  __syncthreads();
  // phase B: wave w -> (ntile w&7, K-half w>>3); one b1 load, two MFMAs per kstep
  int nt1 = w & 7, half = w >> 3;
  floatx4 accA = (floatx4){0.f,0.f,0.f,0.f};
  floatx4 accB = (floatx4){0.f,0.f,0.f,0.f};
  const short8* Bp = (const short8*)Bf;
  int kb = half*32, ke = kb + 32;
  #pragma unroll 8
  for(int kk=kb;kk<ke;kk++){
    int ai = (kk*64 + (l^(kk>>2)))*8;
    short8 a0 = *(const short8*)(&ldsA[ai]);
    short8 a1 = *(const short8*)(&ldsA[32768 + ai]);
    short8 b1 = Bp[(size_t)(kk*8+nt1)*64 + l];
    accA = __builtin_amdgcn_mfma_f32_16x16x32_bf16(a0, b1, accA, 0,0,0);
    accB = __builtin_amdgcn_mfma_f32_16x16x32_bf16(a1, b1, accB, 0,0,0);
  }
  #pragma unroll
  for(int t=0;t<2;t++){
    int kk = 64 + half*2 + t;
    uint4 za0 = *(const uint4*)(zib + (size_t)(n0+col)*128 + (kk-64)*32 + quad*8);
    uint4 za1 = *(const uint4*)(zib + (size_t)(n0+16+col)*128 + (kk-64)*32 + quad*8);
    union { short8 s; uint4 u; } A0, A1; A0.u = za0; A1.u = za1;
    short8 b1 = Bp[(size_t)(kk*8+nt1)*64 + l];
    accA = __builtin_amdgcn_mfma_f32_16x16x32_bf16(A0.s, b1, accA, 0,0,0);
    accB = __builtin_amdgcn_mfma_f32_16x16x32_bf16(A1.s, b1, accB, 0,0,0);
  }
  __syncthreads();   // all ldsA reads done -> reuse: red (16 KB) + zb/hb tiles after it
  float* red = (float*)ldsA;                               // [0, 16384)
  float* zbA = (float*)((char*)ldsA + 16384);              // 16*132 floats
  float* zbB = zbA + 16*132;
  float* hbA = zbB + 16*132;
  float* hbB = hbA + 16*132;                               // ends at ~50 KB < 128 KB
  if(half==1){
    *(floatx4*)(&red[(nt1*64 + l)*4])     = accA;
    *(floatx4*)(&red[((8+nt1)*64 + l)*4]) = accB;
  }
  __syncthreads();
  if(half==0){
    floatx4 o0 = *(const floatx4*)(&red[(nt1*64 + l)*4]);
    floatx4 o1 = *(const floatx4*)(&red[((8+nt1)*64 + l)*4]);
    int d1 = nt1*16 + col;
    float bv = bias[d1];
    #pragma unroll
    for(int reg=0;reg<4;reg++){
      int row = quad*4 + reg;
      zbA[row*132 + d1] = siluf(accA[reg] + o0[reg] + bv);
      zbB[row*132 + d1] = siluf(accB[reg] + o1[reg] + bv);
    }
  }
  __syncthreads();
  // onsite: group grp = w>>3 -> mtile grp; wl = w&7 -> ntile wl (one per wave)
  int grp = w>>3, wl = w&7;
  float* zb = grp ? zbB : zbA;
  float* hb = grp ? hbB : hbA;
  int m = col, q = quad;
  for(int j=0;j<3;j++){
    const short8* Ba = (const short8*)Waf + (size_t)j*2048 + l;
    floatx4 acc = (floatx4){0.f,0.f,0.f,0.f};
    #pragma unroll
    for(int kk=0;kk<4;kk++){
      const float* zp = zb + m*132 + kk*32 + q*8;
      float4 a0 = *(const float4*)zp, a1 = *(const float4*)(zp+4);
      union { short8 s; uint32_t u[4]; } A;
      A.u[0]=packbf(a0.x,a0.y); A.u[1]=packbf(a0.z,a0.w);
      A.u[2]=packbf(a1.x,a1.y); A.u[3]=packbf(a1.z,a1.w);
      short8 bfr = Ba[(size_t)(kk*8 + wl)*64];
      acc = __builtin_amdgcn_mfma_f32_16x16x32_bf16(A.s, bfr, acc, 0,0,0);
    }
    {
      int dim = wl*16 + m;
      float bv = ba[j*128+dim];
      #pragma unroll
      for(int reg=0;reg<4;reg++)
        hb[(q*4+reg)*132 + dim] = siluf(acc[reg] + bv);
    }
    __syncthreads();
    const short8* Bb = (const short8*)Wbf + (size_t)j*2048 + l;
    floatx4 acc2 = (floatx4){0.f,0.f,0.f,0.f};
    #pragma unroll
    for(int kk=0;kk<4;kk++){
      const float* hp = hb + m*132 + kk*32 + q*8;
      float4 a0 = *(const float4*)hp, a1 = *(const float4*)(hp+4);
      union { short8 s; uint32_t u[4]; } A;
      A.u[0]=packbf(a0.x,a0.y); A.u[1]=packbf(a0.z,a0.w);
      A.u[2]=packbf(a1.x,a1.y); A.u[3]=packbf(a1.z,a1.w);
      short8 bfr = Bb[(size_t)(kk*8 + wl)*64];
      acc2 = __builtin_amdgcn_mfma_f32_16x16x32_bf16(A.s, bfr, acc2, 0,0,0);
    }
    {
      int dim = wl*16 + m;
      float bv = bb[j*128+dim];
      #pragma unroll
      for(int reg=0;reg<4;reg++){
        int idx = (q*4+reg)*132 + dim;
        zb[idx] = zb[idx] + acc2[reg] + bv;
      }
    }
    __syncthreads();
  }
  // final store: per group, 512 threads cover 16 nodes x 128 dims
  {
    int md = *modep;
    const long ZIS = (long)NNODES*128;
    int tig = wl*64 + l;                 // 0..511 within group
    int flat = tig*4, node = flat>>7, k = flat&127;
    float4 v = *(float4*)(zb + node*132 + k);
    int n = n0 + grp*16 + node;
    if(md==1){
      uint2 pv = make_uint2(packbf(v.x,v.y), packbf(v.z,v.w));
      uint16_t* ob = (uint16_t*)outb;
      *(uint2*)(ob + ZIS + 128 + (long)n*256 + k) = pv;   // stack layer 1
      *(uint2*)(ob + (long)n*128 + k) = pv;               // final zi
    } else {
      float* ob = (float*)outb;
      *(float4*)(ob + ZIS + 128 + (long)n*256 + k) = v;
      *(float4*)(ob + (long)n*128 + k) = v;
    }
  }
}

extern "C" void kernel_launch(void* const* d_in, const int* in_sizes, int n_in,
                              void* d_out, int out_size, void* d_ws, size_t ws_size,
                              hipStream_t stream){
  const int* species = (const int*)d_in[0];
  const int* esrc    = (const int*)d_in[1];
  const int* edst    = (const int*)d_in[2];
  const void* dist   = d_in[3];
  const void* swit   = d_in[4];
  const void* Z      = d_in[5];
  const void* Ws0    = d_in[6];
  const void* bs0    = d_in[7];
  const void* V0     = d_in[8];
  const void* Ws1    = d_in[9];
  const void* bs1    = d_in[10];
  const void* V1     = d_in[11];
  const void* Wa     = d_in[12];
  const void* ba     = d_in[13];
  const void* Wb     = d_in[14];
  const void* bb     = d_in[15];

  char* ws = (char*)d_ws;
  size_t off = 0;
  auto alloc = [&](size_t bytes)->void*{ void* p = ws + off; off = (off + bytes + 255) & ~(size_t)255; return p; };
  int*      offs = (int*)     alloc((size_t)(NNODES+1)*4);
  int*      cur  = (int*)     alloc((size_t)NNODES*4);
  int*      dsts = (int*)     alloc((size_t)NEDGES*4);
  int*      sps  = (int*)     alloc((size_t)NEDGES*4);
  uint16_t* gs   = (uint16_t*)alloc((size_t)NEDGES*16*2);      // 12.8 MB
  uint16_t* zib  = (uint16_t*)alloc((size_t)NNODES*128*2);     // 5.12 MB
  uint16_t* zib2 = (uint16_t*)alloc((size_t)NNODES*128*2);     // 5.12 MB (transposed)
  float*    ZWs0 = (float*)   alloc((size_t)51*128*4);
  uint16_t* zfb  = (uint16_t*)alloc((size_t)51*16*2);
  float*    conv = (float*)   alloc((size_t)N_CONV*4);         // 2.04 MB
  uint16_t* Bf0  = (uint16_t*)alloc((size_t)8*8*64*8*2);       // 64 KB
  uint16_t* Bf1  = (uint16_t*)alloc((size_t)KS1*8*64*8*2);     // 557 KB
  uint16_t* Wfr  = (uint16_t*)alloc((size_t)12*16384*2);       // 384 KB
  int*      mode = (int*)     alloc(256);

  const int EB = (NEDGES+255)/256;
  hipMemsetAsync(cur, 0, NNODES*4, stream);
  k_probe<<<1,64,0,stream>>>(dist, mode);
  k_conv <<<(N_CONV+255)/256,256,0,stream>>>(V0, Ws1, bs1, V1, Wa, ba, Wb, bb, mode, conv);
  k_hist <<<EB,256,0,stream>>>(esrc, cur);
  k_scan <<<1,1024,0,stream>>>(cur, offs);
  k_fillG<<<EB,256,0,stream>>>(esrc, edst, species, cur, dist, swit, mode, dsts, sps, gs);
  k_spec <<<51,128,0,stream>>>(Z, Ws0, bs0, mode, ZWs0, zfb);
  k_prepB<<<(8*8*64+255)/256,256,0,stream>>>(conv+OFF_V0, 8,  Bf0);
  k_prepB<<<(64*8*64+255)/256,256,0,stream>>>(conv+OFF_V1, 64, Bf1);
  k_prepB<<<(4*8*64+255)/256,256,0,stream>>>(conv+OFF_WS1, 4, Bf1 + (size_t)64*8*64*8);
  k_prepW<<<(12*2048+255)/256,256,0,stream>>>(conv, Wfr);

  uint16_t* WaF0 = Wfr;
  uint16_t* WaF1 = Wfr + (size_t)3*16384;
  uint16_t* WbF0 = Wfr + (size_t)6*16384;
  uint16_t* WbF1 = Wfr + (size_t)9*16384;

  // layer 0 fused (msg + onsite) -> d_out stack[0], zib, zib2
  k_l0<<<MTILES,256,0,stream>>>(offs, sps, gs, zfb, Bf0, species, ZWs0,
                                WaF0, conv+OFF_BA, WbF0, conv+OFF_BB,
                                d_out, mode, zib, zib2);

  // layer 1 fused (msg incl. zself ksteps + onsite) -> d_out final + stack[1]
  k_l1<<<MT2,1024,0,stream>>>(offs, dsts, gs, zib, zib2, Bf1, conv+OFF_BS1,
                              WaF1, conv+OFF_BA+384, WbF1, conv+OFF_BB+384,
                              d_out, mode);
}

// Round 6
// 287.217 us; speedup vs baseline: 1.0345x; 1.0345x over previous
//
#include <hip/hip_runtime.h>
#include <stdint.h>

#define NNODES 20000
#define NEDGES 400000
#define MTILES 1250   // 20000/16
#define MT2    625    // 20000/32 (k_msg1f: 2 mtiles per block)
#define KS1 68        // layer-1 msg GEMM ksteps: 64 (T@V1) + 4 (zi@Ws1)

typedef __attribute__((ext_vector_type(8))) short short8;
typedef __attribute__((ext_vector_type(4))) float floatx4;

__device__ __forceinline__ float bf2f(uint16_t u){ return __uint_as_float(((uint32_t)u)<<16); }
__device__ __forceinline__ uint16_t f2bf(float f){
  uint32_t x = __float_as_uint(f);
  x += 0x7FFFu + ((x>>16)&1u);
  return (uint16_t)(x>>16);
}
__device__ __forceinline__ uint32_t packbf(float a, float b){
  return (uint32_t)f2bf(a) | ((uint32_t)f2bf(b)<<16);
}
__device__ __forceinline__ float siluf(float x){ return x/(1.0f+__expf(-x)); }
__device__ __forceinline__ float ldf(const void* p, int i, int md){
  return (md==1) ? bf2f(((const uint16_t*)p)[i]) : ((const float*)p)[i];
}

// converted-weights layout (float elements within conv buffer)
#define OFF_V0   0
#define N_V0     32768
#define OFF_WS1  32768
#define N_WS1    16384
#define OFF_BS1  49152
#define N_BS1    128
#define OFF_V1   49280
#define N_V1     262144
#define OFF_WA   311424
#define N_WA     98304
#define OFF_BA   409728
#define N_BA     768
#define OFF_WB   410496
#define N_WB     98304
#define OFF_BB   508800
#define N_BB     768
#define N_CONV   509568

// ---------------- dtype probe ----------------
__global__ void k_probe(const void* dist, int* mode){
  if(threadIdx.x != 0 || blockIdx.x != 0) return;
  const float* f = (const float*)dist;
  const uint16_t* h = (const uint16_t*)dist;
  int okf = 1, okb = 1;
  for(int i=0;i<256;i++){
    float a = f[i];       okf &= (a >= 0.7f) & (a <= 5.1f);
    float b = bf2f(h[i]); okb &= (b >= 0.7f) & (b <= 5.1f);
  }
  *mode = okb ? 1 : (okf ? 0 : 1);
}

// ---------------- convert all weight tensors to fp32 ----------------
__global__ __launch_bounds__(256) void k_conv(const void* s0,const void* s1,const void* s2,const void* s3,
                                              const void* s4,const void* s5,const void* s6,const void* s7,
                                              const int* __restrict__ modep, float* __restrict__ dst){
  int md = *modep;
  int i = blockIdx.x*256 + threadIdx.x;
  if(i >= N_CONV) return;
  const void* src; int t = i;
  if(t < N_V0){src=s0;}
  else if((t-=N_V0) < N_WS1){src=s1;}
  else if((t-=N_WS1) < N_BS1){src=s2;}
  else if((t-=N_BS1) < N_V1){src=s3;}
  else if((t-=N_V1) < N_WA){src=s4;}
  else if((t-=N_WA) < N_BA){src=s5;}
  else if((t-=N_BA) < N_WB){src=s6;}
  else {t-=N_WB; src=s7;}
  dst[i] = ldf(src, t, md);
}

// ---------------- CSR build ----------------
__global__ __launch_bounds__(256) void k_hist(const int* __restrict__ src, int* __restrict__ cnt){
  int e = blockIdx.x*256 + threadIdx.x;
  if(e < NEDGES){
    int s = src[e];
    if((unsigned)s < NNODES) atomicAdd(&cnt[s], 1);
  }
}

// parallel scan: 1024 threads, chunk=20/thread; wave shuffle-scan + LDS cross-wave scan
__global__ __launch_bounds__(1024) void k_scan(int* cnt_cur, int* offs){
  __shared__ int wsum[16];
  int t = threadIdx.x;
  const int chunk = (NNODES + 1023)/1024;   // 20
  int lo = t*chunk, hi = lo+chunk;
  if(lo > NNODES) lo = NNODES;
  if(hi > NNODES) hi = NNODES;
  int s = 0;
  for(int i=lo;i<hi;i++) s += cnt_cur[i];
  int lane = t&63, wv = t>>6;
  int v = s;
  #pragma unroll
  for(int d=1; d<64; d<<=1){
    int u = __shfl_up(v, d);
    if(lane >= d) v += u;
  }
  if(lane==63) wsum[wv] = v;
  __syncthreads();
  if(t==0){
    int run = 0;
    #pragma unroll
    for(int i=0;i<16;i++){ int c = wsum[i]; wsum[i] = run; run += c; }
  }
  __syncthreads();
  int run = wsum[wv] + (v - s);   // exclusive prefix of this thread's chunk
  for(int i=lo;i<hi;i++){
    int c = cnt_cur[i];
    offs[i] = run;
    cnt_cur[i] = run;
    run += c;
  }
  if(t==1023) offs[NNODES] = run;  // thread 1023's chunk is empty -> run == total == NEDGES
}

// ---------------- fused CSR-fill + radial basis (k_fill + k_G) ----------------
__global__ __launch_bounds__(256) void k_fillG(const int* __restrict__ src,
                                               const int* __restrict__ edst,
                                               const int* __restrict__ species,
                                               int* __restrict__ cur,
                                               const void* __restrict__ dist,
                                               const void* __restrict__ sw,
                                               const int* __restrict__ modep,
                                               int* __restrict__ dsts,
                                               int* __restrict__ sps,
                                               uint16_t* __restrict__ gs){
  int e = blockIdx.x*256 + threadIdx.x;
  if(e >= NEDGES) return;
  int md = *modep;
  int s = src[e];
  if((unsigned)s >= NNODES) s = 0;
  int p = atomicAdd(&cur[s], 1);
  if((unsigned)p >= NEDGES) p = 0;
  int dn = edst[e];
  if((unsigned)dn >= NNODES) dn = 0;
  dsts[p] = dn;
  int sp = species[dn];
  if((unsigned)sp >= 51) sp = 0;
  sps[p] = sp;
  float r = ldf(dist, e, md);
  float w = ldf(sw, e, md);
  float rinv = 1.0f/r;
  const float sigma = 0.8f/15.0f;
  const float isig  = 15.0f/0.8f;
  uint32_t u[8];
  #pragma unroll
  for(int j=0;j<8;j++){
    float mu0 = 0.2f + sigma*(float)(2*j);
    float mu1 = 0.2f + sigma*(float)(2*j+1);
    float t0 = (rinv-mu0)*isig, t1 = (rinv-mu1)*isig;
    u[j] = packbf(w*__expf(-0.5f*t0*t0), w*__expf(-0.5f*t1*t1));
  }
  uint4* o = (uint4*)(gs + (size_t)p*16);
  o[0] = make_uint4(u[0],u[1],u[2],u[3]);
  o[1] = make_uint4(u[4],u[5],u[6],u[7]);
}

// ---------------- species tables: ZWs0 fp32, zfb bf16 (51x16) ----------------
__global__ __launch_bounds__(128) void k_spec(const void* __restrict__ Z,
                                              const void* __restrict__ Ws0,
                                              const void* __restrict__ bs0,
                                              const int* __restrict__ modep,
                                              float* __restrict__ ZWs0,
                                              uint16_t* __restrict__ zfb){
  int s = blockIdx.x, d = threadIdx.x;
  int md = *modep;
  float zk[16];
  #pragma unroll
  for(int k=0;k<16;k++) zk[k] = ldf(Z, s*16+k, md);
  float a = ldf(bs0, d, md);
  #pragma unroll
  for(int k=0;k<16;k++) a = fmaf(zk[k], ldf(Ws0, k*128+d, md), a);
  ZWs0[s*128+d] = a;
  if(d < 16) zfb[s*16+d] = f2bf(zk[d]);
}

// ---------------- pack W (Kx128 fp32) into MFMA B-fragment layout, bf16 ----------------
__global__ __launch_bounds__(256) void k_prepB(const float* __restrict__ W, int Ksteps,
                                               uint16_t* __restrict__ Bf){
  int idx = blockIdx.x*256 + threadIdx.x;
  int total = Ksteps*8*64;
  if(idx >= total) return;
  int l = idx & 63, nt = (idx>>6)&7, kk = idx>>9;
  int kbase = kk*32 + (l>>4)*8;
  int dim = nt*16 + (l&15);
  uint32_t u[4];
  #pragma unroll
  for(int t=0;t<4;t++){
    float f0 = W[(size_t)(kbase+2*t)*128 + dim];
    float f1 = W[(size_t)(kbase+2*t+1)*128 + dim];
    u[t] = packbf(f0,f1);
  }
  ((uint4*)Bf)[idx] = make_uint4(u[0],u[1],u[2],u[3]);
}

// pack all 12 onsite 128x128 weights into frags
__global__ __launch_bounds__(256) void k_prepW(const float* __restrict__ conv,
                                               uint16_t* __restrict__ Wf){
  int idx = blockIdx.x*256 + threadIdx.x;
  if(idx >= 12*2048) return;
  int wi = idx>>11, r = idx&2047;
  int l = r & 63, nt = (r>>6)&7, kk = r>>9;
  const float* W = conv + ((wi<6) ? (OFF_WA + wi*16384) : (OFF_WB + (wi-6)*16384));
  int kbase = kk*32 + (l>>4)*8;
  int dim = nt*16 + (l&15);
  uint32_t u[4];
  #pragma unroll
  for(int t=0;t<4;t++){
    float f0 = W[(size_t)(kbase+2*t)*128 + dim];
    float f1 = W[(size_t)(kbase+2*t+1)*128 + dim];
    u[t] = packbf(f0,f1);
  }
  ((uint4*)Wf)[idx] = make_uint4(u[0],u[1],u[2],u[3]);
}

// ---------------- layer-0 FUSED: msg (MFMA scatter + GEMM) + onsite, one block = one mtile ----
// Kept from R5 (l0 fusion ~neutral-positive; 42 KB LDS -> 3 blocks/CU).
__global__ __launch_bounds__(256) void k_l0(const int* __restrict__ offs,
                                            const int* __restrict__ sps,
                                            const uint16_t* __restrict__ gs,
                                            const uint16_t* __restrict__ zfb,
                                            const uint16_t* __restrict__ Bf,
                                            const int* __restrict__ species,
                                            const float* __restrict__ ZWs0,
                                            const uint16_t* __restrict__ Waf,
                                            const float* __restrict__ ba,
                                            const uint16_t* __restrict__ Wbf,
                                            const float* __restrict__ bb,
                                            void* __restrict__ outb,
                                            const int* __restrict__ modep,
                                            uint16_t* __restrict__ zib,
                                            uint16_t* __restrict__ zib2){
  __shared__ uint16_t ldsA[8*64*8];   // 8 KB
  __shared__ float zb[16*132];
  __shared__ float hb[16*132];
  int w = threadIdx.x>>6, l = threadIdx.x&63;
  int n0 = blockIdx.x*16;
  int col = l&15, quad = l>>4;
  // phase A: 4 nodes per wave
  for(int i=0;i<4;i++){
    int m = w*4 + i;
    int n = n0 + m;
    int beg = offs[n], end = offs[n+1];
    floatx4 acc0 = (floatx4){0.f,0.f,0.f,0.f};
    for(int p0=beg; p0<end; p0+=32){
      int sp[8];
      union { short8 s; uint16_t u[8]; } Bg, Az;
      #pragma unroll
      for(int j=0;j<8;j++){
        int p = p0 + quad*8 + j;
        int pc = p < end ? p : beg;
        sp[j] = sps[pc];
        uint16_t g = gs[(size_t)pc*16 + col];
        Bg.u[j] = (p < end) ? g : (uint16_t)0;
      }
      #pragma unroll
      for(int j=0;j<8;j++)
        Az.u[j] = zfb[sp[j]*16 + col];
      acc0 = __builtin_amdgcn_mfma_f32_16x16x32_bf16(Az.s, Bg.s, acc0, 0,0,0);
    }
    int K0 = col*16 + quad*4;
    int kk = K0>>5, qt = (K0>>3)&3, jt = K0&7;
    int slot = kk*64 + ((qt*16 + m) ^ (kk>>2));
    uint32_t lo = packbf(acc0[0], acc0[1]);
    uint32_t hi = packbf(acc0[2], acc0[3]);
    *(uint2*)(&ldsA[slot*8 + jt]) = make_uint2(lo, hi);
  }
  __syncthreads();
  // phase B: wave w -> ntiles w and w+4
  floatx4 acc1 = (floatx4){0.f,0.f,0.f,0.f};
  floatx4 acc2 = (floatx4){0.f,0.f,0.f,0.f};
  const short8* Bp = (const short8*)Bf;
  int nt1 = w, nt2 = w+4;
  #pragma unroll
  for(int kk=0;kk<8;kk++){
    short8 a = *(const short8*)(&ldsA[(kk*64 + (l^(kk>>2)))*8]);
    short8 b1 = Bp[(size_t)(kk*8+nt1)*64 + l];
    short8 b2 = Bp[(size_t)(kk*8+nt2)*64 + l];
    acc1 = __builtin_amdgcn_mfma_f32_16x16x32_bf16(a, b1, acc1, 0,0,0);
    acc2 = __builtin_amdgcn_mfma_f32_16x16x32_bf16(a, b2, acc2, 0,0,0);
  }
  // epilogue -> LDS zb (silu(msg + zself))
  #pragma unroll
  for(int reg=0;reg<4;reg++){
    int node = n0 + quad*4 + reg;
    int sp = species[node];
    if((unsigned)sp >= 51) sp = 0;
    int d1 = nt1*16 + col, d2 = nt2*16 + col;
    int row = quad*4 + reg;
    zb[row*132 + d1] = siluf(acc1[reg] + ZWs0[sp*128 + d1]);
    zb[row*132 + d2] = siluf(acc2[reg] + ZWs0[sp*128 + d2]);
  }
  __syncthreads();
  // onsite: 3 x (h = silu(z@Wa+ba); z += h@Wb+bb); wave w -> ntiles 2w, 2w+1
  int m = col, q = quad;
  for(int j=0;j<3;j++){
    const short8* Ba = (const short8*)Waf + (size_t)j*2048 + l;
    floatx4 acc[2];
    acc[0] = (floatx4){0.f,0.f,0.f,0.f};
    acc[1] = (floatx4){0.f,0.f,0.f,0.f};
    #pragma unroll
    for(int kk=0;kk<4;kk++){
      const float* zp = zb + m*132 + kk*32 + q*8;
      float4 a0 = *(const float4*)zp, a1 = *(const float4*)(zp+4);
      union { short8 s; uint32_t u[4]; } A;
      A.u[0]=packbf(a0.x,a0.y); A.u[1]=packbf(a0.z,a0.w);
      A.u[2]=packbf(a1.x,a1.y); A.u[3]=packbf(a1.z,a1.w);
      #pragma unroll
      for(int t=0;t<2;t++){
        short8 bfr = Ba[(size_t)(kk*8 + w*2+t)*64];
        acc[t] = __builtin_amdgcn_mfma_f32_16x16x32_bf16(A.s, bfr, acc[t], 0,0,0);
      }
    }
    #pragma unroll
    for(int t=0;t<2;t++){
      int dim = (w*2+t)*16 + m;
      float bv = ba[j*128+dim];
      #pragma unroll
      for(int reg=0;reg<4;reg++)
        hb[(q*4+reg)*132 + dim] = siluf(acc[t][reg] + bv);
    }
    __syncthreads();
    const short8* Bb = (const short8*)Wbf + (size_t)j*2048 + l;
    floatx4 acc2o[2];
    acc2o[0] = (floatx4){0.f,0.f,0.f,0.f};
    acc2o[1] = (floatx4){0.f,0.f,0.f,0.f};
    #pragma unroll
    for(int kk=0;kk<4;kk++){
      const float* hp = hb + m*132 + kk*32 + q*8;
      float4 a0 = *(const float4*)hp, a1 = *(const float4*)(hp+4);
      union { short8 s; uint32_t u[4]; } A;
      A.u[0]=packbf(a0.x,a0.y); A.u[1]=packbf(a0.z,a0.w);
      A.u[2]=packbf(a1.x,a1.y); A.u[3]=packbf(a1.z,a1.w);
      #pragma unroll
      for(int t=0;t<2;t++){
        short8 bfr = Bb[(size_t)(kk*8 + w*2+t)*64];
        acc2o[t] = __builtin_amdgcn_mfma_f32_16x16x32_bf16(A.s, bfr, acc2o[t], 0,0,0);
      }
    }
    #pragma unroll
    for(int t=0;t<2;t++){
      int dim = (w*2+t)*16 + m;
      float bv = bb[j*128+dim];
      #pragma unroll
      for(int reg=0;reg<4;reg++){
        int idx = (q*4+reg)*132 + dim;
        zb[idx] = zb[idx] + acc2o[t][reg] + bv;
      }
    }
    __syncthreads();
  }
  // final store: out(stack layer0), zib, zib2 (NO fp32 zi)
  int md = *modep;
  const long ZIS = (long)NNODES*128;
  #pragma unroll
  for(int i=0;i<2;i++){
    int flat = (i*256 + threadIdx.x)*4;
    int node = flat>>7, k = flat&127;
    float4 v = *(float4*)(zb + node*132 + k);
    int n = n0 + node;
    uint2 pv = make_uint2(packbf(v.x,v.y), packbf(v.z,v.w));
    *(uint2*)(zib + (size_t)n*128 + k) = pv;
    if(md==1){
      uint16_t* ob = (uint16_t*)outb;
      *(uint2*)(ob + ZIS + (long)n*256 + k) = pv;
    } else {
      float* ob = (float*)outb;
      *(float4*)(ob + ZIS + (long)n*256 + k) = v;
    }
  }
  {
    int node2 = threadIdx.x>>4, c = threadIdx.x&15;
    float vv[8];
    #pragma unroll
    for(int mt=0;mt<8;mt++) vv[mt] = zb[node2*132 + mt*16 + c];
    uint4 o = make_uint4(packbf(vv[0],vv[1]), packbf(vv[2],vv[3]),
                         packbf(vv[4],vv[5]), packbf(vv[6],vv[7]));
    *(uint4*)(zib2 + (size_t)(n0+node2)*128 + c*8) = o;
  }
}

// ---------------- layer-1 msg (R3 version, SPLIT from onsite): 2 mtiles, split-K ----------
// R5 post-mortem: fusing onsite into this kernel cost ~9 us (barrier-lockstep onsite at
// 1 block/CU vs standalone onsite at 4-5 blocks/CU). Reverted to the proven R3 split.
__global__ __launch_bounds__(1024, 2) void k_msg1f(const int* __restrict__ offs,
                                               const int* __restrict__ dsts,
                                               const uint16_t* __restrict__ gs,
                                               const uint16_t* __restrict__ zib,   // linear, ksteps 64..67
                                               const uint16_t* __restrict__ zib2,  // transposed, gathers
                                               const uint16_t* __restrict__ Bf,
                                               const float* __restrict__ bias,
                                               float* __restrict__ zacc){
  __shared__ __align__(16) uint16_t ldsA[2*64*64*8];   // 128 KB: two 64-KB A-tiles
  int w = threadIdx.x>>6, l = threadIdx.x&63;
  int n0 = blockIdx.x*32;
  int col = l&15, quad = l>>4;
  // phase A: 2 nodes per wave
  for(int i=0;i<2;i++){
    int m = w*2 + i;            // 0..31
    int n = n0 + m;
    int beg = offs[n], end = offs[n+1];
    floatx4 acc[8];
    #pragma unroll
    for(int t=0;t<8;t++) acc[t] = (floatx4){0.f,0.f,0.f,0.f};
    for(int p0=beg; p0<end; p0+=32){
      int dn[8];
      union { short8 s; uint16_t u[8]; } Bg;
      #pragma unroll
      for(int j=0;j<8;j++){
        int p = p0 + quad*8 + j;
        int pc = p < end ? p : beg;
        dn[j] = dsts[pc];
        uint16_t g = gs[(size_t)pc*16 + col];
        Bg.u[j] = (p < end) ? g : (uint16_t)0;
      }
      uint4 row[8];
      #pragma unroll
      for(int j=0;j<8;j++)
        row[j] = *(const uint4*)(zib2 + (size_t)dn[j]*128 + col*8);
      #pragma unroll
      for(int mt=0;mt<8;mt++){
        union { short8 s; uint32_t u32[4]; } Az;
        #pragma unroll
        for(int cp=0;cp<4;cp++){
          uint32_t a = ((const uint32_t*)&row[2*cp])[mt>>1];
          uint32_t b = ((const uint32_t*)&row[2*cp+1])[mt>>1];
          Az.u32[cp] = __builtin_amdgcn_perm(b, a, (mt&1) ? 0x07060302u : 0x05040100u);
        }
        acc[mt] = __builtin_amdgcn_mfma_f32_16x16x32_bf16(Az.s, Bg.s, acc[mt], 0,0,0);
      }
    }
    uint16_t* tile = ldsA + (size_t)(m>>4)*32768;
    int mloc = m & 15;
    #pragma unroll
    for(int mt=0;mt<8;mt++){
      int K0 = col*128 + mt*16 + quad*4;
      int kk = K0>>5, qt = (K0>>3)&3, jt = K0&7;
      int slot = kk*64 + ((qt*16 + mloc) ^ (kk>>2));
      uint32_t lo = packbf(acc[mt][0], acc[mt][1]);
      uint32_t hi = packbf(acc[mt][2], acc[mt][3]);
      *(uint2*)(&tile[slot*8 + jt]) = make_uint2(lo, hi);
    }
  }
  __syncthreads();
  // phase B: wave w -> (ntile w&7, K-half w>>3); one b1 load, two MFMAs per kstep
  int nt1 = w & 7, half = w >> 3;
  floatx4 accA = (floatx4){0.f,0.f,0.f,0.f};
  floatx4 accB = (floatx4){0.f,0.f,0.f,0.f};
  const short8* Bp = (const short8*)Bf;
  int kb = half*32, ke = kb + 32;
  #pragma unroll 8
  for(int kk=kb;kk<ke;kk++){
    int ai = (kk*64 + (l^(kk>>2)))*8;
    short8 a0 = *(const short8*)(&ldsA[ai]);
    short8 a1 = *(const short8*)(&ldsA[32768 + ai]);
    short8 b1 = Bp[(size_t)(kk*8+nt1)*64 + l];
    accA = __builtin_amdgcn_mfma_f32_16x16x32_bf16(a0, b1, accA, 0,0,0);
    accB = __builtin_amdgcn_mfma_f32_16x16x32_bf16(a1, b1, accB, 0,0,0);
  }
  #pragma unroll
  for(int t=0;t<2;t++){
    int kk = 64 + half*2 + t;
    uint4 za0 = *(const uint4*)(zib + (size_t)(n0+col)*128 + (kk-64)*32 + quad*8);
    uint4 za1 = *(const uint4*)(zib + (size_t)(n0+16+col)*128 + (kk-64)*32 + quad*8);
    union { short8 s; uint4 u; } A0, A1; A0.u = za0; A1.u = za1;
    short8 b1 = Bp[(size_t)(kk*8+nt1)*64 + l];
    accA = __builtin_amdgcn_mfma_f32_16x16x32_bf16(A0.s, b1, accA, 0,0,0);
    accB = __builtin_amdgcn_mfma_f32_16x16x32_bf16(A1.s, b1, accB, 0,0,0);
  }
  __syncthreads();   // all ldsA reads done -> safe to reuse for reduction (16 KB)
  float* red = (float*)ldsA;
  if(half==1){
    *(floatx4*)(&red[(nt1*64 + l)*4])     = accA;
    *(floatx4*)(&red[((8+nt1)*64 + l)*4]) = accB;
  }
  __syncthreads();
  if(half==0){
    floatx4 o0 = *(const floatx4*)(&red[(nt1*64 + l)*4]);
    floatx4 o1 = *(const floatx4*)(&red[((8+nt1)*64 + l)*4]);
    int d1 = nt1*16 + col;
    float bv = bias[d1];
    #pragma unroll
    for(int reg=0;reg<4;reg++){
      int nodeA = n0 + quad*4 + reg;
      int nodeB = n0 + 16 + quad*4 + reg;
      zacc[(size_t)nodeA*128 + d1] = siluf(accA[reg] + o0[reg] + bv);
      zacc[(size_t)nodeB*128 + d1] = siluf(accB[reg] + o1[reg] + bv);
    }
  }
}

// ---------------- layer-1 standalone onsite: 3 x (h=silu(z@Wa+ba); z+=h@Wb+bb) ----------
// 256 thr = 4 waves = one mtile; 33 KB LDS -> 4-5 blocks/CU (the occupancy that made the
// split beat the fused version). Reads zacc; writes d_out stack[1] + final only (the fp32
// write-back of R3 was a dead store -- removed).
__global__ __launch_bounds__(256) void k_onsite1(const float* __restrict__ zin,
                                                 const uint16_t* __restrict__ Waf,
                                                 const float* __restrict__ ba,
                                                 const uint16_t* __restrict__ Wbf,
                                                 const float* __restrict__ bb,
                                                 void* __restrict__ outb,
                                                 const int* __restrict__ modep){
  __shared__ float zb[16*132];
  __shared__ float hb[16*132];
  int w = threadIdx.x>>6, l = threadIdx.x&63;
  int n0 = blockIdx.x*16;
  int md = *modep;
  #pragma unroll
  for(int i=0;i<2;i++){
    int flat = (i*256 + threadIdx.x)*4;
    int node = flat>>7, k = flat&127;
    *(float4*)(zb + node*132 + k) = *(const float4*)(zin + (size_t)(n0+node)*128 + k);
  }
  __syncthreads();
  int m = l&15, q = l>>4;
  for(int j=0;j<3;j++){
    const short8* Ba = (const short8*)Waf + (size_t)j*2048 + l;
    floatx4 acc[2];
    acc[0] = (floatx4){0.f,0.f,0.f,0.f};
    acc[1] = (floatx4){0.f,0.f,0.f,0.f};
    #pragma unroll
    for(int kk=0;kk<4;kk++){
      const float* zp = zb + m*132 + kk*32 + q*8;
      float4 a0 = *(const float4*)zp, a1 = *(const float4*)(zp+4);
      union { short8 s; uint32_t u[4]; } A;
      A.u[0]=packbf(a0.x,a0.y); A.u[1]=packbf(a0.z,a0.w);
      A.u[2]=packbf(a1.x,a1.y); A.u[3]=packbf(a1.z,a1.w);
      #pragma unroll
      for(int t=0;t<2;t++){
        short8 bfr = Ba[(size_t)(kk*8 + w*2+t)*64];
        acc[t] = __builtin_amdgcn_mfma_f32_16x16x32_bf16(A.s, bfr, acc[t], 0,0,0);
      }
    }
    #pragma unroll
    for(int t=0;t<2;t++){
      int dim = (w*2+t)*16 + m;
      float bv = ba[j*128+dim];
      #pragma unroll
      for(int reg=0;reg<4;reg++)
        hb[(q*4+reg)*132 + dim] = siluf(acc[t][reg] + bv);
    }
    __syncthreads();
    const short8* Bb = (const short8*)Wbf + (size_t)j*2048 + l;
    floatx4 acc2[2];
    acc2[0] = (floatx4){0.f,0.f,0.f,0.f};
    acc2[1] = (floatx4){0.f,0.f,0.f,0.f};
    #pragma unroll
    for(int kk=0;kk<4;kk++){
      const float* hp = hb + m*132 + kk*32 + q*8;
      float4 a0 = *(const float4*)hp, a1 = *(const float4*)(hp+4);
      union { short8 s; uint32_t u[4]; } A;
      A.u[0]=packbf(a0.x,a0.y); A.u[1]=packbf(a0.z,a0.w);
      A.u[2]=packbf(a1.x,a1.y); A.u[3]=packbf(a1.z,a1.w);
      #pragma unroll
      for(int t=0;t<2;t++){
        short8 bfr = Bb[(size_t)(kk*8 + w*2+t)*64];
        acc2[t] = __builtin_amdgcn_mfma_f32_16x16x32_bf16(A.s, bfr, acc2[t], 0,0,0);
      }
    }
    #pragma unroll
    for(int t=0;t<2;t++){
      int dim = (w*2+t)*16 + m;
      float bv = bb[j*128+dim];
      #pragma unroll
      for(int reg=0;reg<4;reg++){
        int idx = (q*4+reg)*132 + dim;
        zb[idx] = zb[idx] + acc2[t][reg] + bv;
      }
    }
    __syncthreads();
  }
  // final store: d_out stack[1] + final zi
  const long ZIS = (long)NNODES*128;
  #pragma unroll
  for(int i=0;i<2;i++){
    int flat = (i*256 + threadIdx.x)*4;
    int node = flat>>7, k = flat&127;
    float4 v = *(float4*)(zb + node*132 + k);
    int n = n0 + node;
    if(md==1){
      uint2 pv = make_uint2(packbf(v.x,v.y), packbf(v.z,v.w));
      uint16_t* ob = (uint16_t*)outb;
      *(uint2*)(ob + ZIS + 128 + (long)n*256 + k) = pv;   // stack layer 1
      *(uint2*)(ob + (long)n*128 + k) = pv;               // final zi
    } else {
      float* ob = (float*)outb;
      *(float4*)(ob + ZIS + 128 + (long)n*256 + k) = v;
      *(float4*)(ob + (long)n*128 + k) = v;
    }
  }
}

extern "C" void kernel_launch(void* const* d_in, const int* in_sizes, int n_in,
                              void* d_out, int out_size, void* d_ws, size_t ws_size,
                              hipStream_t stream){
  const int* species = (const int*)d_in[0];
  const int* esrc    = (const int*)d_in[1];
  const int* edst    = (const int*)d_in[2];
  const void* dist   = d_in[3];
  const void* swit   = d_in[4];
  const void* Z      = d_in[5];
  const void* Ws0    = d_in[6];
  const void* bs0    = d_in[7];
  const void* V0     = d_in[8];
  const void* Ws1    = d_in[9];
  const void* bs1    = d_in[10];
  const void* V1     = d_in[11];
  const void* Wa     = d_in[12];
  const void* ba     = d_in[13];
  const void* Wb     = d_in[14];
  const void* bb     = d_in[15];

  char* ws = (char*)d_ws;
  size_t off = 0;
  auto alloc = [&](size_t bytes)->void*{ void* p = ws + off; off = (off + bytes + 255) & ~(size_t)255; return p; };
  int*      offs = (int*)     alloc((size_t)(NNODES+1)*4);
  int*      cur  = (int*)     alloc((size_t)NNODES*4);
  int*      dsts = (int*)     alloc((size_t)NEDGES*4);
  int*      sps  = (int*)     alloc((size_t)NEDGES*4);
  uint16_t* gs   = (uint16_t*)alloc((size_t)NEDGES*16*2);      // 12.8 MB
  float*    zacc = (float*)   alloc((size_t)NNODES*128*4);     // 10.24 MB
  uint16_t* zib  = (uint16_t*)alloc((size_t)NNODES*128*2);     // 5.12 MB
  uint16_t* zib2 = (uint16_t*)alloc((size_t)NNODES*128*2);     // 5.12 MB (transposed)
  float*    ZWs0 = (float*)   alloc((size_t)51*128*4);
  uint16_t* zfb  = (uint16_t*)alloc((size_t)51*16*2);
  float*    conv = (float*)   alloc((size_t)N_CONV*4);         // 2.04 MB
  uint16_t* Bf0  = (uint16_t*)alloc((size_t)8*8*64*8*2);       // 64 KB
  uint16_t* Bf1  = (uint16_t*)alloc((size_t)KS1*8*64*8*2);     // 557 KB
  uint16_t* Wfr  = (uint16_t*)alloc((size_t)12*16384*2);       // 384 KB
  int*      mode = (int*)     alloc(256);

  const int EB = (NEDGES+255)/256;
  hipMemsetAsync(cur, 0, NNODES*4, stream);
  k_probe<<<1,64,0,stream>>>(dist, mode);
  k_conv <<<(N_CONV+255)/256,256,0,stream>>>(V0, Ws1, bs1, V1, Wa, ba, Wb, bb, mode, conv);
  k_hist <<<EB,256,0,stream>>>(esrc, cur);
  k_scan <<<1,1024,0,stream>>>(cur, offs);
  k_fillG<<<EB,256,0,stream>>>(esrc, edst, species, cur, dist, swit, mode, dsts, sps, gs);
  k_spec <<<51,128,0,stream>>>(Z, Ws0, bs0, mode, ZWs0, zfb);
  k_prepB<<<(8*8*64+255)/256,256,0,stream>>>(conv+OFF_V0, 8,  Bf0);
  k_prepB<<<(64*8*64+255)/256,256,0,stream>>>(conv+OFF_V1, 64, Bf1);
  k_prepB<<<(4*8*64+255)/256,256,0,stream>>>(conv+OFF_WS1, 4, Bf1 + (size_t)64*8*64*8);
  k_prepW<<<(12*2048+255)/256,256,0,stream>>>(conv, Wfr);

  uint16_t* WaF0 = Wfr;
  uint16_t* WaF1 = Wfr + (size_t)3*16384;
  uint16_t* WbF0 = Wfr + (size_t)6*16384;
  uint16_t* WbF1 = Wfr + (size_t)9*16384;

  // layer 0 fused (msg + onsite) -> d_out stack[0], zib, zib2
  k_l0<<<MTILES,256,0,stream>>>(offs, sps, gs, zfb, Bf0, species, ZWs0,
                                WaF0, conv+OFF_BA, WbF0, conv+OFF_BB,
                                d_out, mode, zib, zib2);

  // layer 1: msg (split) -> zacc, then standalone onsite -> d_out final + stack[1]
  k_msg1f<<<MT2,1024,0,stream>>>(offs, dsts, gs, zib, zib2, Bf1, conv+OFF_BS1, zacc);
  k_onsite1<<<MTILES,256,0,stream>>>(zacc, WaF1, conv+OFF_BA+384, WbF1, conv+OFF_BB+384,
                                     d_out, mode);
}

// Round 7
// 270.245 us; speedup vs baseline: 1.0995x; 1.0628x over previous
//
#include <hip/hip_runtime.h>
#include <stdint.h>

#define NNODES 20000
#define NEDGES 400000
#define MTILES 1250   // 20000/16
#define MT2    625    // 20000/32 (k_msg1f: 2 mtiles per block)
#define KS1 68        // layer-1 msg GEMM ksteps: 64 (T@V1) + 4 (zi@Ws1)

typedef __attribute__((ext_vector_type(8))) short short8;
typedef __attribute__((ext_vector_type(4))) float floatx4;

__device__ __forceinline__ float bf2f(uint16_t u){ return __uint_as_float(((uint32_t)u)<<16); }
__device__ __forceinline__ uint16_t f2bf(float f){
  uint32_t x = __float_as_uint(f);
  x += 0x7FFFu + ((x>>16)&1u);
  return (uint16_t)(x>>16);
}
__device__ __forceinline__ uint32_t packbf(float a, float b){
  return (uint32_t)f2bf(a) | ((uint32_t)f2bf(b)<<16);
}
__device__ __forceinline__ float siluf(float x){ return x/(1.0f+__expf(-x)); }
__device__ __forceinline__ float ldf(const void* p, long i, int md){
  return (md==1) ? bf2f(((const uint16_t*)p)[i]) : ((const float*)p)[i];
}

// ---------------- merged prep kernel block ranges ----------------
#define B_HIST 1563                       // ceil(400000/256) hist blocks
#define B_PB1  128                        // prepB V1 (64 ksteps): 32768 idx
#define B_PB0  16                         // prepB V0 (8 ksteps): 4096 idx
#define B_PBS  8                          // prepB Ws1 (4 ksteps): 2048 idx
#define B_PW   96                         // prepW 12 matrices: 24576 idx
#define B_SPEC 26                         // 51 species, 2 per block
#define B_BIAS 7                          // 1664 bias floats
#define B_PREP (B_HIST+B_PB1+B_PB0+B_PBS+B_PW+B_SPEC+B_BIAS)   // 1844

// fragment math on per-matrix index `ridx` (< Ksteps*512), output at global slot `oslot`
__device__ __forceinline__ void prepB_one(const void* W, long base, int md,
                                          int ridx, int oslot, uint16_t* Bf){
  int l = ridx & 63, nt = (ridx>>6)&7, kk = ridx>>9;
  int kbase = kk*32 + (l>>4)*8;
  int dim = nt*16 + (l&15);
  uint32_t u[4];
  #pragma unroll
  for(int t=0;t<4;t++){
    float f0 = ldf(W, base + (long)(kbase+2*t)*128 + dim, md);
    float f1 = ldf(W, base + (long)(kbase+2*t+1)*128 + dim, md);
    u[t] = packbf(f0,f1);
  }
  ((uint4*)Bf)[oslot] = make_uint4(u[0],u[1],u[2],u[3]);
}

// ---------------- ONE prep launch: hist + probe + conv + spec + prepB x3 + prepW ----------
// R7: collapses 7 tiny launches (probe, conv, hist, spec, prepB x3, prepW) into 1.
// Each non-hist block computes `mode` LOCALLY (64 lanes x 4 probes + __all) -- this removes
// the probe->conv->prep serial launch chain. prepB/prepW/spec read RAW inputs via ldf
// (flat layouts identical to the old conv staging buffer). Only the 1664 bias floats are
// fp32-staged (B_BIAS range), which also publishes *mode for downstream kernels.
__global__ __launch_bounds__(256) void k_prep(const int* __restrict__ esrc,
                                              int* __restrict__ cnt,
                                              const void* __restrict__ dist,
                                              const void* __restrict__ V0,
                                              const void* __restrict__ Ws1,
                                              const void* __restrict__ V1,
                                              const void* __restrict__ Wa,
                                              const void* __restrict__ Wb,
                                              const void* __restrict__ Z,
                                              const void* __restrict__ Ws0,
                                              const void* __restrict__ bs0,
                                              const void* __restrict__ ba,
                                              const void* __restrict__ bb,
                                              const void* __restrict__ bs1,
                                              uint16_t* __restrict__ Bf0,
                                              uint16_t* __restrict__ Bf1,
                                              uint16_t* __restrict__ Wfr,
                                              float* __restrict__ ZWs0,
                                              uint16_t* __restrict__ zfb,
                                              float* __restrict__ biasbuf,
                                              int* __restrict__ mode){
  int b = blockIdx.x;
  int tid = threadIdx.x;
  if(b < B_HIST){               // ---- hist ----
    int e = b*256 + tid;
    if(e < NEDGES){
      int s = esrc[e];
      if((unsigned)s < NNODES) atomicAdd(&cnt[s], 1);
    }
    return;
  }
  b -= B_HIST;
  // ---- local dtype probe (wave 0), broadcast via LDS ----
  __shared__ int smode;
  if(tid < 64){
    const float* f = (const float*)dist;
    const uint16_t* h = (const uint16_t*)dist;
    int okf = 1, okb = 1;
    #pragma unroll
    for(int i=0;i<4;i++){
      int ix = tid*4 + i;
      float a = f[ix];        okf &= (a >= 0.7f) & (a <= 5.1f);
      float bx = bf2f(h[ix]); okb &= (bx >= 0.7f) & (bx <= 5.1f);
    }
    okf = __all(okf); okb = __all(okb);
    if(tid==0) smode = okb ? 1 : (okf ? 0 : 1);
  }
  __syncthreads();
  int md = smode;
  if(b < B_PB1){                // ---- prepB: V1 -> Bf1 ksteps 0..63 ----
    int idx = b*256 + tid;
    prepB_one(V1, 0, md, idx, idx, Bf1);
    return;
  }
  b -= B_PB1;
  if(b < B_PB0){                // ---- prepB: V0 -> Bf0 ----
    int idx = b*256 + tid;
    prepB_one(V0, 0, md, idx, idx, Bf0);
    return;
  }
  b -= B_PB0;
  if(b < B_PBS){                // ---- prepB: Ws1 -> Bf1 ksteps 64..67 ----
    int idx = b*256 + tid;
    prepB_one(Ws1, 0, md, idx, idx, Bf1 + (size_t)64*8*64*8);
    return;
  }
  b -= B_PBS;
  if(b < B_PW){                 // ---- prepW: Wa/Wb -> Wfr (per-matrix masked index) ----
    int idx = b*256 + tid;
    int wi = idx>>11, r = idx & 2047;
    const void* src = (wi<6) ? Wa : Wb;
    long base = (long)((wi<6) ? wi : wi-6)*16384;
    prepB_one(src, base, md, r, idx, Wfr);
    return;
  }
  b -= B_PW;
  if(b < B_SPEC){               // ---- spec: ZWs0 + zfb ----
    int s = b*2 + (tid>>7), d = tid&127;
    if(s < 51){
      float zk[16];
      #pragma unroll
      for(int k=0;k<16;k++) zk[k] = ldf(Z, s*16+k, md);
      float a = ldf(bs0, d, md);
      #pragma unroll
      for(int k=0;k<16;k++) a = fmaf(zk[k], ldf(Ws0, k*128+d, md), a);
      ZWs0[s*128+d] = a;
      if(d < 16) zfb[s*16+d] = f2bf(zk[d]);
    }
    return;
  }
  b -= B_SPEC;
  {                             // ---- biases -> fp32 biasbuf; publish mode ----
    int i = b*256 + tid;
    if(i < 1664){
      float v;
      if(i < 768)       v = ldf(ba, i, md);
      else if(i < 1536) v = ldf(bb, i-768, md);
      else              v = ldf(bs1, i-1536, md);
      biasbuf[i] = v;
    }
    if(b==0 && tid==0) *mode = md;
  }
}

// ---------------- CSR scan (unchanged) ----------------
__global__ __launch_bounds__(1024) void k_scan(int* cnt_cur, int* offs){
  __shared__ int wsum[16];
  int t = threadIdx.x;
  const int chunk = (NNODES + 1023)/1024;   // 20
  int lo = t*chunk, hi = lo+chunk;
  if(lo > NNODES) lo = NNODES;
  if(hi > NNODES) hi = NNODES;
  int s = 0;
  for(int i=lo;i<hi;i++) s += cnt_cur[i];
  int lane = t&63, wv = t>>6;
  int v = s;
  #pragma unroll
  for(int d=1; d<64; d<<=1){
    int u = __shfl_up(v, d);
    if(lane >= d) v += u;
  }
  if(lane==63) wsum[wv] = v;
  __syncthreads();
  if(t==0){
    int run = 0;
    #pragma unroll
    for(int i=0;i<16;i++){ int c = wsum[i]; wsum[i] = run; run += c; }
  }
  __syncthreads();
  int run = wsum[wv] + (v - s);
  for(int i=lo;i<hi;i++){
    int c = cnt_cur[i];
    offs[i] = run;
    cnt_cur[i] = run;
    run += c;
  }
  if(t==1023) offs[NNODES] = run;
}

// ---------------- fused CSR-fill + radial basis (unchanged) ----------------
__global__ __launch_bounds__(256) void k_fillG(const int* __restrict__ src,
                                               const int* __restrict__ edst,
                                               const int* __restrict__ species,
                                               int* __restrict__ cur,
                                               const void* __restrict__ dist,
                                               const void* __restrict__ sw,
                                               const int* __restrict__ modep,
                                               int* __restrict__ dsts,
                                               int* __restrict__ sps,
                                               uint16_t* __restrict__ gs){
  int e = blockIdx.x*256 + threadIdx.x;
  if(e >= NEDGES) return;
  int md = *modep;
  int s = src[e];
  if((unsigned)s >= NNODES) s = 0;
  int p = atomicAdd(&cur[s], 1);
  if((unsigned)p >= NEDGES) p = 0;
  int dn = edst[e];
  if((unsigned)dn >= NNODES) dn = 0;
  dsts[p] = dn;
  int sp = species[dn];
  if((unsigned)sp >= 51) sp = 0;
  sps[p] = sp;
  float r = ldf(dist, e, md);
  float w = ldf(sw, e, md);
  float rinv = 1.0f/r;
  const float sigma = 0.8f/15.0f;
  const float isig  = 15.0f/0.8f;
  uint32_t u[8];
  #pragma unroll
  for(int j=0;j<8;j++){
    float mu0 = 0.2f + sigma*(float)(2*j);
    float mu1 = 0.2f + sigma*(float)(2*j+1);
    float t0 = (rinv-mu0)*isig, t1 = (rinv-mu1)*isig;
    u[j] = packbf(w*__expf(-0.5f*t0*t0), w*__expf(-0.5f*t1*t1));
  }
  uint4* o = (uint4*)(gs + (size_t)p*16);
  o[0] = make_uint4(u[0],u[1],u[2],u[3]);
  o[1] = make_uint4(u[4],u[5],u[6],u[7]);
}

// ---------------- layer-0 FUSED: msg + onsite (unchanged from R6) ----------------
__global__ __launch_bounds__(256) void k_l0(const int* __restrict__ offs,
                                            const int* __restrict__ sps,
                                            const uint16_t* __restrict__ gs,
                                            const uint16_t* __restrict__ zfb,
                                            const uint16_t* __restrict__ Bf,
                                            const int* __restrict__ species,
                                            const float* __restrict__ ZWs0,
                                            const uint16_t* __restrict__ Waf,
                                            const float* __restrict__ ba,
                                            const uint16_t* __restrict__ Wbf,
                                            const float* __restrict__ bb,
                                            void* __restrict__ outb,
                                            const int* __restrict__ modep,
                                            uint16_t* __restrict__ zib,
                                            uint16_t* __restrict__ zib2){
  __shared__ uint16_t ldsA[8*64*8];   // 8 KB
  __shared__ float zb[16*132];
  __shared__ float hb[16*132];
  int w = threadIdx.x>>6, l = threadIdx.x&63;
  int n0 = blockIdx.x*16;
  int col = l&15, quad = l>>4;
  for(int i=0;i<4;i++){
    int m = w*4 + i;
    int n = n0 + m;
    int beg = offs[n], end = offs[n+1];
    floatx4 acc0 = (floatx4){0.f,0.f,0.f,0.f};
    for(int p0=beg; p0<end; p0+=32){
      int sp[8];
      union { short8 s; uint16_t u[8]; } Bg, Az;
      #pragma unroll
      for(int j=0;j<8;j++){
        int p = p0 + quad*8 + j;
        int pc = p < end ? p : beg;
        sp[j] = sps[pc];
        uint16_t g = gs[(size_t)pc*16 + col];
        Bg.u[j] = (p < end) ? g : (uint16_t)0;
      }
      #pragma unroll
      for(int j=0;j<8;j++)
        Az.u[j] = zfb[sp[j]*16 + col];
      acc0 = __builtin_amdgcn_mfma_f32_16x16x32_bf16(Az.s, Bg.s, acc0, 0,0,0);
    }
    int K0 = col*16 + quad*4;
    int kk = K0>>5, qt = (K0>>3)&3, jt = K0&7;
    int slot = kk*64 + ((qt*16 + m) ^ (kk>>2));
    uint32_t lo = packbf(acc0[0], acc0[1]);
    uint32_t hi = packbf(acc0[2], acc0[3]);
    *(uint2*)(&ldsA[slot*8 + jt]) = make_uint2(lo, hi);
  }
  __syncthreads();
  floatx4 acc1 = (floatx4){0.f,0.f,0.f,0.f};
  floatx4 acc2 = (floatx4){0.f,0.f,0.f,0.f};
  const short8* Bp = (const short8*)Bf;
  int nt1 = w, nt2 = w+4;
  #pragma unroll
  for(int kk=0;kk<8;kk++){
    short8 a = *(const short8*)(&ldsA[(kk*64 + (l^(kk>>2)))*8]);
    short8 b1 = Bp[(size_t)(kk*8+nt1)*64 + l];
    short8 b2 = Bp[(size_t)(kk*8+nt2)*64 + l];
    acc1 = __builtin_amdgcn_mfma_f32_16x16x32_bf16(a, b1, acc1, 0,0,0);
    acc2 = __builtin_amdgcn_mfma_f32_16x16x32_bf16(a, b2, acc2, 0,0,0);
  }
  #pragma unroll
  for(int reg=0;reg<4;reg++){
    int node = n0 + quad*4 + reg;
    int sp = species[node];
    if((unsigned)sp >= 51) sp = 0;
    int d1 = nt1*16 + col, d2 = nt2*16 + col;
    int row = quad*4 + reg;
    zb[row*132 + d1] = siluf(acc1[reg] + ZWs0[sp*128 + d1]);
    zb[row*132 + d2] = siluf(acc2[reg] + ZWs0[sp*128 + d2]);
  }
  __syncthreads();
  int m = col, q = quad;
  for(int j=0;j<3;j++){
    const short8* Ba = (const short8*)Waf + (size_t)j*2048 + l;
    floatx4 acc[2];
    acc[0] = (floatx4){0.f,0.f,0.f,0.f};
    acc[1] = (floatx4){0.f,0.f,0.f,0.f};
    #pragma unroll
    for(int kk=0;kk<4;kk++){
      const float* zp = zb + m*132 + kk*32 + q*8;
      float4 a0 = *(const float4*)zp, a1 = *(const float4*)(zp+4);
      union { short8 s; uint32_t u[4]; } A;
      A.u[0]=packbf(a0.x,a0.y); A.u[1]=packbf(a0.z,a0.w);
      A.u[2]=packbf(a1.x,a1.y); A.u[3]=packbf(a1.z,a1.w);
      #pragma unroll
      for(int t=0;t<2;t++){
        short8 bfr = Ba[(size_t)(kk*8 + w*2+t)*64];
        acc[t] = __builtin_amdgcn_mfma_f32_16x16x32_bf16(A.s, bfr, acc[t], 0,0,0);
      }
    }
    #pragma unroll
    for(int t=0;t<2;t++){
      int dim = (w*2+t)*16 + m;
      float bv = ba[j*128+dim];
      #pragma unroll
      for(int reg=0;reg<4;reg++)
        hb[(q*4+reg)*132 + dim] = siluf(acc[t][reg] + bv);
    }
    __syncthreads();
    const short8* Bb = (const short8*)Wbf + (size_t)j*2048 + l;
    floatx4 acc2o[2];
    acc2o[0] = (floatx4){0.f,0.f,0.f,0.f};
    acc2o[1] = (floatx4){0.f,0.f,0.f,0.f};
    #pragma unroll
    for(int kk=0;kk<4;kk++){
      const float* hp = hb + m*132 + kk*32 + q*8;
      float4 a0 = *(const float4*)hp, a1 = *(const float4*)(hp+4);
      union { short8 s; uint32_t u[4]; } A;
      A.u[0]=packbf(a0.x,a0.y); A.u[1]=packbf(a0.z,a0.w);
      A.u[2]=packbf(a1.x,a1.y); A.u[3]=packbf(a1.z,a1.w);
      #pragma unroll
      for(int t=0;t<2;t++){
        short8 bfr = Bb[(size_t)(kk*8 + w*2+t)*64];
        acc2o[t] = __builtin_amdgcn_mfma_f32_16x16x32_bf16(A.s, bfr, acc2o[t], 0,0,0);
      }
    }
    #pragma unroll
    for(int t=0;t<2;t++){
      int dim = (w*2+t)*16 + m;
      float bv = bb[j*128+dim];
      #pragma unroll
      for(int reg=0;reg<4;reg++){
        int idx = (q*4+reg)*132 + dim;
        zb[idx] = zb[idx] + acc2o[t][reg] + bv;
      }
    }
    __syncthreads();
  }
  int md = *modep;
  const long ZIS = (long)NNODES*128;
  #pragma unroll
  for(int i=0;i<2;i++){
    int flat = (i*256 + threadIdx.x)*4;
    int node = flat>>7, k = flat&127;
    float4 v = *(float4*)(zb + node*132 + k);
    int n = n0 + node;
    uint2 pv = make_uint2(packbf(v.x,v.y), packbf(v.z,v.w));
    *(uint2*)(zib + (size_t)n*128 + k) = pv;
    if(md==1){
      uint16_t* ob = (uint16_t*)outb;
      *(uint2*)(ob + ZIS + (long)n*256 + k) = pv;
    } else {
      float* ob = (float*)outb;
      *(float4*)(ob + ZIS + (long)n*256 + k) = v;
    }
  }
  {
    int node2 = threadIdx.x>>4, c = threadIdx.x&15;
    float vv[8];
    #pragma unroll
    for(int mt=0;mt<8;mt++) vv[mt] = zb[node2*132 + mt*16 + c];
    uint4 o = make_uint4(packbf(vv[0],vv[1]), packbf(vv[2],vv[3]),
                         packbf(vv[4],vv[5]), packbf(vv[6],vv[7]));
    *(uint4*)(zib2 + (size_t)(n0+node2)*128 + c*8) = o;
  }
}

// ---------------- layer-1 msg (unchanged from R6) ----------------
__global__ __launch_bounds__(1024, 2) void k_msg1f(const int* __restrict__ offs,
                                               const int* __restrict__ dsts,
                                               const uint16_t* __restrict__ gs,
                                               const uint16_t* __restrict__ zib,
                                               const uint16_t* __restrict__ zib2,
                                               const uint16_t* __restrict__ Bf,
                                               const float* __restrict__ bias,
                                               float* __restrict__ zacc){
  __shared__ __align__(16) uint16_t ldsA[2*64*64*8];   // 128 KB
  int w = threadIdx.x>>6, l = threadIdx.x&63;
  int n0 = blockIdx.x*32;
  int col = l&15, quad = l>>4;
  for(int i=0;i<2;i++){
    int m = w*2 + i;
    int n = n0 + m;
    int beg = offs[n], end = offs[n+1];
    floatx4 acc[8];
    #pragma unroll
    for(int t=0;t<8;t++) acc[t] = (floatx4){0.f,0.f,0.f,0.f};
    for(int p0=beg; p0<end; p0+=32){
      int dn[8];
      union { short8 s; uint16_t u[8]; } Bg;
      #pragma unroll
      for(int j=0;j<8;j++){
        int p = p0 + quad*8 + j;
        int pc = p < end ? p : beg;
        dn[j] = dsts[pc];
        uint16_t g = gs[(size_t)pc*16 + col];
        Bg.u[j] = (p < end) ? g : (uint16_t)0;
      }
      uint4 row[8];
      #pragma unroll
      for(int j=0;j<8;j++)
        row[j] = *(const uint4*)(zib2 + (size_t)dn[j]*128 + col*8);
      #pragma unroll
      for(int mt=0;mt<8;mt++){
        union { short8 s; uint32_t u32[4]; } Az;
        #pragma unroll
        for(int cp=0;cp<4;cp++){
          uint32_t a = ((const uint32_t*)&row[2*cp])[mt>>1];
          uint32_t b = ((const uint32_t*)&row[2*cp+1])[mt>>1];
          Az.u32[cp] = __builtin_amdgcn_perm(b, a, (mt&1) ? 0x07060302u : 0x05040100u);
        }
        acc[mt] = __builtin_amdgcn_mfma_f32_16x16x32_bf16(Az.s, Bg.s, acc[mt], 0,0,0);
      }
    }
    uint16_t* tile = ldsA + (size_t)(m>>4)*32768;
    int mloc = m & 15;
    #pragma unroll
    for(int mt=0;mt<8;mt++){
      int K0 = col*128 + mt*16 + quad*4;
      int kk = K0>>5, qt = (K0>>3)&3, jt = K0&7;
      int slot = kk*64 + ((qt*16 + mloc) ^ (kk>>2));
      uint32_t lo = packbf(acc[mt][0], acc[mt][1]);
      uint32_t hi = packbf(acc[mt][2], acc[mt][3]);
      *(uint2*)(&tile[slot*8 + jt]) = make_uint2(lo, hi);
    }
  }
  __syncthreads();
  int nt1 = w & 7, half = w >> 3;
  floatx4 accA = (floatx4){0.f,0.f,0.f,0.f};
  floatx4 accB = (floatx4){0.f,0.f,0.f,0.f};
  const short8* Bp = (const short8*)Bf;
  int kb = half*32, ke = kb + 32;
  #pragma unroll 8
  for(int kk=kb;kk<ke;kk++){
    int ai = (kk*64 + (l^(kk>>2)))*8;
    short8 a0 = *(const short8*)(&ldsA[ai]);
    short8 a1 = *(const short8*)(&ldsA[32768 + ai]);
    short8 b1 = Bp[(size_t)(kk*8+nt1)*64 + l];
    accA = __builtin_amdgcn_mfma_f32_16x16x32_bf16(a0, b1, accA, 0,0,0);
    accB = __builtin_amdgcn_mfma_f32_16x16x32_bf16(a1, b1, accB, 0,0,0);
  }
  #pragma unroll
  for(int t=0;t<2;t++){
    int kk = 64 + half*2 + t;
    uint4 za0 = *(const uint4*)(zib + (size_t)(n0+col)*128 + (kk-64)*32 + quad*8);
    uint4 za1 = *(const uint4*)(zib + (size_t)(n0+16+col)*128 + (kk-64)*32 + quad*8);
    union { short8 s; uint4 u; } A0, A1; A0.u = za0; A1.u = za1;
    short8 b1 = Bp[(size_t)(kk*8+nt1)*64 + l];
    accA = __builtin_amdgcn_mfma_f32_16x16x32_bf16(A0.s, b1, accA, 0,0,0);
    accB = __builtin_amdgcn_mfma_f32_16x16x32_bf16(A1.s, b1, accB, 0,0,0);
  }
  __syncthreads();
  float* red = (float*)ldsA;
  if(half==1){
    *(floatx4*)(&red[(nt1*64 + l)*4])     = accA;
    *(floatx4*)(&red[((8+nt1)*64 + l)*4]) = accB;
  }
  __syncthreads();
  if(half==0){
    floatx4 o0 = *(const floatx4*)(&red[(nt1*64 + l)*4]);
    floatx4 o1 = *(const floatx4*)(&red[((8+nt1)*64 + l)*4]);
    int d1 = nt1*16 + col;
    float bv = bias[d1];
    #pragma unroll
    for(int reg=0;reg<4;reg++){
      int nodeA = n0 + quad*4 + reg;
      int nodeB = n0 + 16 + quad*4 + reg;
      zacc[(size_t)nodeA*128 + d1] = siluf(accA[reg] + o0[reg] + bv);
      zacc[(size_t)nodeB*128 + d1] = siluf(accB[reg] + o1[reg] + bv);
    }
  }
}

// ---------------- layer-1 standalone onsite (unchanged from R6) ----------------
__global__ __launch_bounds__(256) void k_onsite1(const float* __restrict__ zin,
                                                 const uint16_t* __restrict__ Waf,
                                                 const float* __restrict__ ba,
                                                 const uint16_t* __restrict__ Wbf,
                                                 const float* __restrict__ bb,
                                                 void* __restrict__ outb,
                                                 const int* __restrict__ modep){
  __shared__ float zb[16*132];
  __shared__ float hb[16*132];
  int w = threadIdx.x>>6, l = threadIdx.x&63;
  int n0 = blockIdx.x*16;
  int md = *modep;
  #pragma unroll
  for(int i=0;i<2;i++){
    int flat = (i*256 + threadIdx.x)*4;
    int node = flat>>7, k = flat&127;
    *(float4*)(zb + node*132 + k) = *(const float4*)(zin + (size_t)(n0+node)*128 + k);
  }
  __syncthreads();
  int m = l&15, q = l>>4;
  for(int j=0;j<3;j++){
    const short8* Ba = (const short8*)Waf + (size_t)j*2048 + l;
    floatx4 acc[2];
    acc[0] = (floatx4){0.f,0.f,0.f,0.f};
    acc[1] = (floatx4){0.f,0.f,0.f,0.f};
    #pragma unroll
    for(int kk=0;kk<4;kk++){
      const float* zp = zb + m*132 + kk*32 + q*8;
      float4 a0 = *(const float4*)zp, a1 = *(const float4*)(zp+4);
      union { short8 s; uint32_t u[4]; } A;
      A.u[0]=packbf(a0.x,a0.y); A.u[1]=packbf(a0.z,a0.w);
      A.u[2]=packbf(a1.x,a1.y); A.u[3]=packbf(a1.z,a1.w);
      #pragma unroll
      for(int t=0;t<2;t++){
        short8 bfr = Ba[(size_t)(kk*8 + w*2+t)*64];
        acc[t] = __builtin_amdgcn_mfma_f32_16x16x32_bf16(A.s, bfr, acc[t], 0,0,0);
      }
    }
    #pragma unroll
    for(int t=0;t<2;t++){
      int dim = (w*2+t)*16 + m;
      float bv = ba[j*128+dim];
      #pragma unroll
      for(int reg=0;reg<4;reg++)
        hb[(q*4+reg)*132 + dim] = siluf(acc[t][reg] + bv);
    }
    __syncthreads();
    const short8* Bb = (const short8*)Wbf + (size_t)j*2048 + l;
    floatx4 acc2[2];
    acc2[0] = (floatx4){0.f,0.f,0.f,0.f};
    acc2[1] = (floatx4){0.f,0.f,0.f,0.f};
    #pragma unroll
    for(int kk=0;kk<4;kk++){
      const float* hp = hb + m*132 + kk*32 + q*8;
      float4 a0 = *(const float4*)hp, a1 = *(const float4*)(hp+4);
      union { short8 s; uint32_t u[4]; } A;
      A.u[0]=packbf(a0.x,a0.y); A.u[1]=packbf(a0.z,a0.w);
      A.u[2]=packbf(a1.x,a1.y); A.u[3]=packbf(a1.z,a1.w);
      #pragma unroll
      for(int t=0;t<2;t++){
        short8 bfr = Bb[(size_t)(kk*8 + w*2+t)*64];
        acc2[t] = __builtin_amdgcn_mfma_f32_16x16x32_bf16(A.s, bfr, acc2[t], 0,0,0);
      }
    }
    #pragma unroll
    for(int t=0;t<2;t++){
      int dim = (w*2+t)*16 + m;
      float bv = bb[j*128+dim];
      #pragma unroll
      for(int reg=0;reg<4;reg++){
        int idx = (q*4+reg)*132 + dim;
        zb[idx] = zb[idx] + acc2[t][reg] + bv;
      }
    }
    __syncthreads();
  }
  const long ZIS = (long)NNODES*128;
  #pragma unroll
  for(int i=0;i<2;i++){
    int flat = (i*256 + threadIdx.x)*4;
    int node = flat>>7, k = flat&127;
    float4 v = *(float4*)(zb + node*132 + k);
    int n = n0 + node;
    if(md==1){
      uint2 pv = make_uint2(packbf(v.x,v.y), packbf(v.z,v.w));
      uint16_t* ob = (uint16_t*)outb;
      *(uint2*)(ob + ZIS + 128 + (long)n*256 + k) = pv;
      *(uint2*)(ob + (long)n*128 + k) = pv;
    } else {
      float* ob = (float*)outb;
      *(float4*)(ob + ZIS + 128 + (long)n*256 + k) = v;
      *(float4*)(ob + (long)n*128 + k) = v;
    }
  }
}

extern "C" void kernel_launch(void* const* d_in, const int* in_sizes, int n_in,
                              void* d_out, int out_size, void* d_ws, size_t ws_size,
                              hipStream_t stream){
  const int* species = (const int*)d_in[0];
  const int* esrc    = (const int*)d_in[1];
  const int* edst    = (const int*)d_in[2];
  const void* dist   = d_in[3];
  const void* swit   = d_in[4];
  const void* Z      = d_in[5];
  const void* Ws0    = d_in[6];
  const void* bs0    = d_in[7];
  const void* V0     = d_in[8];
  const void* Ws1    = d_in[9];
  const void* bs1    = d_in[10];
  const void* V1     = d_in[11];
  const void* Wa     = d_in[12];
  const void* ba     = d_in[13];
  const void* Wb     = d_in[14];
  const void* bb     = d_in[15];

  char* ws = (char*)d_ws;
  size_t off = 0;
  auto alloc = [&](size_t bytes)->void*{ void* p = ws + off; off = (off + bytes + 255) & ~(size_t)255; return p; };
  int*      offs = (int*)     alloc((size_t)(NNODES+1)*4);
  int*      cur  = (int*)     alloc((size_t)NNODES*4);
  int*      dsts = (int*)     alloc((size_t)NEDGES*4);
  int*      sps  = (int*)     alloc((size_t)NEDGES*4);
  uint16_t* gs   = (uint16_t*)alloc((size_t)NEDGES*16*2);      // 12.8 MB
  float*    zacc = (float*)   alloc((size_t)NNODES*128*4);     // 10.24 MB
  uint16_t* zib  = (uint16_t*)alloc((size_t)NNODES*128*2);     // 5.12 MB
  uint16_t* zib2 = (uint16_t*)alloc((size_t)NNODES*128*2);     // 5.12 MB (transposed)
  float*    ZWs0 = (float*)   alloc((size_t)51*128*4);
  uint16_t* zfb  = (uint16_t*)alloc((size_t)51*16*2);
  float*    biasb= (float*)   alloc((size_t)1664*4);           // ba(768) bb(768) bs1(128)
  uint16_t* Bf0  = (uint16_t*)alloc((size_t)8*8*64*8*2);       // 64 KB
  uint16_t* Bf1  = (uint16_t*)alloc((size_t)KS1*8*64*8*2);     // 557 KB
  uint16_t* Wfr  = (uint16_t*)alloc((size_t)12*16384*2);       // 384 KB
  int*      mode = (int*)     alloc(256);

  const int EB = (NEDGES+255)/256;
  hipMemsetAsync(cur, 0, NNODES*4, stream);

  // ONE prep launch (was: probe, conv, hist, spec, prepB x3, prepW = 7 launches)
  k_prep<<<B_PREP,256,0,stream>>>(esrc, cur, dist, V0, Ws1, V1, Wa, Wb,
                                  Z, Ws0, bs0, ba, bb, bs1,
                                  Bf0, Bf1, Wfr, ZWs0, zfb, biasb, mode);
  k_scan <<<1,1024,0,stream>>>(cur, offs);
  k_fillG<<<EB,256,0,stream>>>(esrc, edst, species, cur, dist, swit, mode, dsts, sps, gs);

  uint16_t* WaF0 = Wfr;
  uint16_t* WaF1 = Wfr + (size_t)3*16384;
  uint16_t* WbF0 = Wfr + (size_t)6*16384;
  uint16_t* WbF1 = Wfr + (size_t)9*16384;
  float* BA0 = biasb;            // layer0 onsite-a biases (384)
  float* BA1 = biasb + 384;      // layer1
  float* BB0 = biasb + 768;      // layer0 onsite-b biases
  float* BB1 = biasb + 768 + 384;
  float* BS1 = biasb + 1536;     // layer1 zself bias (128)

  // layer 0 fused (msg + onsite) -> d_out stack[0], zib, zib2
  k_l0<<<MTILES,256,0,stream>>>(offs, sps, gs, zfb, Bf0, species, ZWs0,
                                WaF0, BA0, WbF0, BB0,
                                d_out, mode, zib, zib2);

  // layer 1: msg (split) -> zacc, then standalone onsite -> d_out final + stack[1]
  k_msg1f<<<MT2,1024,0,stream>>>(offs, dsts, gs, zib, zib2, Bf1, BS1, zacc);
  k_onsite1<<<MTILES,256,0,stream>>>(zacc, WaF1, BA1, WbF1, BB1,
                                     d_out, mode);
}

// Round 8
// 267.350 us; speedup vs baseline: 1.1114x; 1.0108x over previous
//
#include <hip/hip_runtime.h>
#include <stdint.h>

#define NNODES 20000
#define NEDGES 400000
#define MTILES 1250   // 20000/16
#define MT2    625    // 20000/32 (k_msg1f: 2 mtiles per block)
#define KS1 68        // layer-1 msg GEMM ksteps: 64 (T@V1) + 4 (zi@Ws1)

typedef __attribute__((ext_vector_type(8))) short short8;
typedef __attribute__((ext_vector_type(4))) float floatx4;

__device__ __forceinline__ float bf2f(uint16_t u){ return __uint_as_float(((uint32_t)u)<<16); }
__device__ __forceinline__ uint16_t f2bf(float f){
  uint32_t x = __float_as_uint(f);
  x += 0x7FFFu + ((x>>16)&1u);
  return (uint16_t)(x>>16);
}
__device__ __forceinline__ uint32_t packbf(float a, float b){
  return (uint32_t)f2bf(a) | ((uint32_t)f2bf(b)<<16);
}
__device__ __forceinline__ float siluf(float x){ return x/(1.0f+__expf(-x)); }
__device__ __forceinline__ float ldf(const void* p, long i, int md){
  return (md==1) ? bf2f(((const uint16_t*)p)[i]) : ((const float*)p)[i];
}

// ---------------- merged prep kernel block ranges ----------------
#define B_HIST 1563                       // ceil(400000/256) hist blocks
#define B_PB1  128                        // prepB V1 (64 ksteps): 32768 idx
#define B_PB0  16                         // prepB V0 (8 ksteps): 4096 idx
#define B_PBS  8                          // prepB Ws1 (4 ksteps): 2048 idx
#define B_PW   96                         // prepW 12 matrices: 24576 idx
#define B_SPEC 26                         // 51 species, 2 per block
#define B_BIAS 7                          // 1664 bias floats
#define B_PREP (B_HIST+B_PB1+B_PB0+B_PBS+B_PW+B_SPEC+B_BIAS)   // 1844

// fragment math on per-matrix index `ridx` (< Ksteps*512), output at global slot `oslot`
__device__ __forceinline__ void prepB_one(const void* W, long base, int md,
                                          int ridx, int oslot, uint16_t* Bf){
  int l = ridx & 63, nt = (ridx>>6)&7, kk = ridx>>9;
  int kbase = kk*32 + (l>>4)*8;
  int dim = nt*16 + (l&15);
  uint32_t u[4];
  #pragma unroll
  for(int t=0;t<4;t++){
    float f0 = ldf(W, base + (long)(kbase+2*t)*128 + dim, md);
    float f1 = ldf(W, base + (long)(kbase+2*t+1)*128 + dim, md);
    u[t] = packbf(f0,f1);
  }
  ((uint4*)Bf)[oslot] = make_uint4(u[0],u[1],u[2],u[3]);
}

// ---------------- ONE prep launch (unchanged from R7) ----------
__global__ __launch_bounds__(256) void k_prep(const int* __restrict__ esrc,
                                              int* __restrict__ cnt,
                                              const void* __restrict__ dist,
                                              const void* __restrict__ V0,
                                              const void* __restrict__ Ws1,
                                              const void* __restrict__ V1,
                                              const void* __restrict__ Wa,
                                              const void* __restrict__ Wb,
                                              const void* __restrict__ Z,
                                              const void* __restrict__ Ws0,
                                              const void* __restrict__ bs0,
                                              const void* __restrict__ ba,
                                              const void* __restrict__ bb,
                                              const void* __restrict__ bs1,
                                              uint16_t* __restrict__ Bf0,
                                              uint16_t* __restrict__ Bf1,
                                              uint16_t* __restrict__ Wfr,
                                              float* __restrict__ ZWs0,
                                              uint16_t* __restrict__ zfb,
                                              float* __restrict__ biasbuf,
                                              int* __restrict__ mode){
  int b = blockIdx.x;
  int tid = threadIdx.x;
  if(b < B_HIST){               // ---- hist ----
    int e = b*256 + tid;
    if(e < NEDGES){
      int s = esrc[e];
      if((unsigned)s < NNODES) atomicAdd(&cnt[s], 1);
    }
    return;
  }
  b -= B_HIST;
  // ---- local dtype probe (wave 0), broadcast via LDS ----
  __shared__ int smode;
  if(tid < 64){
    const float* f = (const float*)dist;
    const uint16_t* h = (const uint16_t*)dist;
    int okf = 1, okb = 1;
    #pragma unroll
    for(int i=0;i<4;i++){
      int ix = tid*4 + i;
      float a = f[ix];        okf &= (a >= 0.7f) & (a <= 5.1f);
      float bx = bf2f(h[ix]); okb &= (bx >= 0.7f) & (bx <= 5.1f);
    }
    okf = __all(okf); okb = __all(okb);
    if(tid==0) smode = okb ? 1 : (okf ? 0 : 1);
  }
  __syncthreads();
  int md = smode;
  if(b < B_PB1){                // ---- prepB: V1 -> Bf1 ksteps 0..63 ----
    int idx = b*256 + tid;
    prepB_one(V1, 0, md, idx, idx, Bf1);
    return;
  }
  b -= B_PB1;
  if(b < B_PB0){                // ---- prepB: V0 -> Bf0 ----
    int idx = b*256 + tid;
    prepB_one(V0, 0, md, idx, idx, Bf0);
    return;
  }
  b -= B_PB0;
  if(b < B_PBS){                // ---- prepB: Ws1 -> Bf1 ksteps 64..67 ----
    int idx = b*256 + tid;
    prepB_one(Ws1, 0, md, idx, idx, Bf1 + (size_t)64*8*64*8);
    return;
  }
  b -= B_PBS;
  if(b < B_PW){                 // ---- prepW: Wa/Wb -> Wfr (per-matrix masked index) ----
    int idx = b*256 + tid;
    int wi = idx>>11, r = idx & 2047;
    const void* src = (wi<6) ? Wa : Wb;
    long base = (long)((wi<6) ? wi : wi-6)*16384;
    prepB_one(src, base, md, r, idx, Wfr);
    return;
  }
  b -= B_PW;
  if(b < B_SPEC){               // ---- spec: ZWs0 + zfb ----
    int s = b*2 + (tid>>7), d = tid&127;
    if(s < 51){
      float zk[16];
      #pragma unroll
      for(int k=0;k<16;k++) zk[k] = ldf(Z, s*16+k, md);
      float a = ldf(bs0, d, md);
      #pragma unroll
      for(int k=0;k<16;k++) a = fmaf(zk[k], ldf(Ws0, k*128+d, md), a);
      ZWs0[s*128+d] = a;
      if(d < 16) zfb[s*16+d] = f2bf(zk[d]);
    }
    return;
  }
  b -= B_SPEC;
  {                             // ---- biases -> fp32 biasbuf; publish mode ----
    int i = b*256 + tid;
    if(i < 1664){
      float v;
      if(i < 768)       v = ldf(ba, i, md);
      else if(i < 1536) v = ldf(bb, i-768, md);
      else              v = ldf(bs1, i-1536, md);
      biasbuf[i] = v;
    }
    if(b==0 && tid==0) *mode = md;
  }
}

// ---------------- CSR scan (unchanged) ----------------
__global__ __launch_bounds__(1024) void k_scan(int* cnt_cur, int* offs){
  __shared__ int wsum[16];
  int t = threadIdx.x;
  const int chunk = (NNODES + 1023)/1024;   // 20
  int lo = t*chunk, hi = lo+chunk;
  if(lo > NNODES) lo = NNODES;
  if(hi > NNODES) hi = NNODES;
  int s = 0;
  for(int i=lo;i<hi;i++) s += cnt_cur[i];
  int lane = t&63, wv = t>>6;
  int v = s;
  #pragma unroll
  for(int d=1; d<64; d<<=1){
    int u = __shfl_up(v, d);
    if(lane >= d) v += u;
  }
  if(lane==63) wsum[wv] = v;
  __syncthreads();
  if(t==0){
    int run = 0;
    #pragma unroll
    for(int i=0;i<16;i++){ int c = wsum[i]; wsum[i] = run; run += c; }
  }
  __syncthreads();
  int run = wsum[wv] + (v - s);
  for(int i=lo;i<hi;i++){
    int c = cnt_cur[i];
    offs[i] = run;
    cnt_cur[i] = run;
    run += c;
  }
  if(t==1023) offs[NNODES] = run;
}

// ---------------- fused CSR-fill + radial basis (unchanged) ----------------
__global__ __launch_bounds__(256) void k_fillG(const int* __restrict__ src,
                                               const int* __restrict__ edst,
                                               const int* __restrict__ species,
                                               int* __restrict__ cur,
                                               const void* __restrict__ dist,
                                               const void* __restrict__ sw,
                                               const int* __restrict__ modep,
                                               int* __restrict__ dsts,
                                               int* __restrict__ sps,
                                               uint16_t* __restrict__ gs){
  int e = blockIdx.x*256 + threadIdx.x;
  if(e >= NEDGES) return;
  int md = *modep;
  int s = src[e];
  if((unsigned)s >= NNODES) s = 0;
  int p = atomicAdd(&cur[s], 1);
  if((unsigned)p >= NEDGES) p = 0;
  int dn = edst[e];
  if((unsigned)dn >= NNODES) dn = 0;
  dsts[p] = dn;
  int sp = species[dn];
  if((unsigned)sp >= 51) sp = 0;
  sps[p] = sp;
  float r = ldf(dist, e, md);
  float w = ldf(sw, e, md);
  float rinv = 1.0f/r;
  const float sigma = 0.8f/15.0f;
  const float isig  = 15.0f/0.8f;
  uint32_t u[8];
  #pragma unroll
  for(int j=0;j<8;j++){
    float mu0 = 0.2f + sigma*(float)(2*j);
    float mu1 = 0.2f + sigma*(float)(2*j+1);
    float t0 = (rinv-mu0)*isig, t1 = (rinv-mu1)*isig;
    u[j] = packbf(w*__expf(-0.5f*t0*t0), w*__expf(-0.5f*t1*t1));
  }
  uint4* o = (uint4*)(gs + (size_t)p*16);
  o[0] = make_uint4(u[0],u[1],u[2],u[3]);
  o[1] = make_uint4(u[4],u[5],u[6],u[7]);
}

// ---------------- layer-0 FUSED: msg + onsite ----------------
// R8: phase A sps loads -> ONE coalesced 64-edge window load + __shfl (was 8 scalar
// broadcast loads per 32-edge group); removes a ~300cyc memory hop from the serial
// sps->zfb->MFMA chain. Everything else unchanged from R7.
__global__ __launch_bounds__(256) void k_l0(const int* __restrict__ offs,
                                            const int* __restrict__ sps,
                                            const uint16_t* __restrict__ gs,
                                            const uint16_t* __restrict__ zfb,
                                            const uint16_t* __restrict__ Bf,
                                            const int* __restrict__ species,
                                            const float* __restrict__ ZWs0,
                                            const uint16_t* __restrict__ Waf,
                                            const float* __restrict__ ba,
                                            const uint16_t* __restrict__ Wbf,
                                            const float* __restrict__ bb,
                                            void* __restrict__ outb,
                                            const int* __restrict__ modep,
                                            uint16_t* __restrict__ zib,
                                            uint16_t* __restrict__ zib2){
  __shared__ uint16_t ldsA[8*64*8];   // 8 KB
  __shared__ float zb[16*132];
  __shared__ float hb[16*132];
  int w = threadIdx.x>>6, l = threadIdx.x&63;
  int n0 = blockIdx.x*16;
  int col = l&15, quad = l>>4;
  for(int i=0;i<4;i++){
    int m = w*4 + i;
    int n = n0 + m;
    int beg = offs[n], end = offs[n+1];
    floatx4 acc0 = (floatx4){0.f,0.f,0.f,0.f};
    for(int w0=beg; w0<end; w0+=64){
      int pidx = w0 + l;
      int spall = (pidx < end) ? sps[pidx] : 0;   // coalesced: 64 edges per wave
      #pragma unroll
      for(int h=0;h<2;h++){
        int p0 = w0 + h*32;
        if(p0 >= end) break;
        union { short8 s; uint16_t u[8]; } Bg, Az;
        int sp[8];
        #pragma unroll
        for(int j=0;j<8;j++){
          int p = p0 + quad*8 + j;
          int pc = p < end ? p : beg;
          sp[j] = __shfl(spall, h*32 + quad*8 + j);
          uint16_t g = gs[(size_t)pc*16 + col];
          Bg.u[j] = (p < end) ? g : (uint16_t)0;
        }
        #pragma unroll
        for(int j=0;j<8;j++)
          Az.u[j] = zfb[sp[j]*16 + col];
        acc0 = __builtin_amdgcn_mfma_f32_16x16x32_bf16(Az.s, Bg.s, acc0, 0,0,0);
      }
    }
    int K0 = col*16 + quad*4;
    int kk = K0>>5, qt = (K0>>3)&3, jt = K0&7;
    int slot = kk*64 + ((qt*16 + m) ^ (kk>>2));
    uint32_t lo = packbf(acc0[0], acc0[1]);
    uint32_t hi = packbf(acc0[2], acc0[3]);
    *(uint2*)(&ldsA[slot*8 + jt]) = make_uint2(lo, hi);
  }
  __syncthreads();
  floatx4 acc1 = (floatx4){0.f,0.f,0.f,0.f};
  floatx4 acc2 = (floatx4){0.f,0.f,0.f,0.f};
  const short8* Bp = (const short8*)Bf;
  int nt1 = w, nt2 = w+4;
  #pragma unroll
  for(int kk=0;kk<8;kk++){
    short8 a = *(const short8*)(&ldsA[(kk*64 + (l^(kk>>2)))*8]);
    short8 b1 = Bp[(size_t)(kk*8+nt1)*64 + l];
    short8 b2 = Bp[(size_t)(kk*8+nt2)*64 + l];
    acc1 = __builtin_amdgcn_mfma_f32_16x16x32_bf16(a, b1, acc1, 0,0,0);
    acc2 = __builtin_amdgcn_mfma_f32_16x16x32_bf16(a, b2, acc2, 0,0,0);
  }
  #pragma unroll
  for(int reg=0;reg<4;reg++){
    int node = n0 + quad*4 + reg;
    int sp = species[node];
    if((unsigned)sp >= 51) sp = 0;
    int d1 = nt1*16 + col, d2 = nt2*16 + col;
    int row = quad*4 + reg;
    zb[row*132 + d1] = siluf(acc1[reg] + ZWs0[sp*128 + d1]);
    zb[row*132 + d2] = siluf(acc2[reg] + ZWs0[sp*128 + d2]);
  }
  __syncthreads();
  int m = col, q = quad;
  for(int j=0;j<3;j++){
    const short8* Ba = (const short8*)Waf + (size_t)j*2048 + l;
    floatx4 acc[2];
    acc[0] = (floatx4){0.f,0.f,0.f,0.f};
    acc[1] = (floatx4){0.f,0.f,0.f,0.f};
    #pragma unroll
    for(int kk=0;kk<4;kk++){
      const float* zp = zb + m*132 + kk*32 + q*8;
      float4 a0 = *(const float4*)zp, a1 = *(const float4*)(zp+4);
      union { short8 s; uint32_t u[4]; } A;
      A.u[0]=packbf(a0.x,a0.y); A.u[1]=packbf(a0.z,a0.w);
      A.u[2]=packbf(a1.x,a1.y); A.u[3]=packbf(a1.z,a1.w);
      #pragma unroll
      for(int t=0;t<2;t++){
        short8 bfr = Ba[(size_t)(kk*8 + w*2+t)*64];
        acc[t] = __builtin_amdgcn_mfma_f32_16x16x32_bf16(A.s, bfr, acc[t], 0,0,0);
      }
    }
    #pragma unroll
    for(int t=0;t<2;t++){
      int dim = (w*2+t)*16 + m;
      float bv = ba[j*128+dim];
      #pragma unroll
      for(int reg=0;reg<4;reg++)
        hb[(q*4+reg)*132 + dim] = siluf(acc[t][reg] + bv);
    }
    __syncthreads();
    const short8* Bb = (const short8*)Wbf + (size_t)j*2048 + l;
    floatx4 acc2o[2];
    acc2o[0] = (floatx4){0.f,0.f,0.f,0.f};
    acc2o[1] = (floatx4){0.f,0.f,0.f,0.f};
    #pragma unroll
    for(int kk=0;kk<4;kk++){
      const float* hp = hb + m*132 + kk*32 + q*8;
      float4 a0 = *(const float4*)hp, a1 = *(const float4*)(hp+4);
      union { short8 s; uint32_t u[4]; } A;
      A.u[0]=packbf(a0.x,a0.y); A.u[1]=packbf(a0.z,a0.w);
      A.u[2]=packbf(a1.x,a1.y); A.u[3]=packbf(a1.z,a1.w);
      #pragma unroll
      for(int t=0;t<2;t++){
        short8 bfr = Bb[(size_t)(kk*8 + w*2+t)*64];
        acc2o[t] = __builtin_amdgcn_mfma_f32_16x16x32_bf16(A.s, bfr, acc2o[t], 0,0,0);
      }
    }
    #pragma unroll
    for(int t=0;t<2;t++){
      int dim = (w*2+t)*16 + m;
      float bv = bb[j*128+dim];
      #pragma unroll
      for(int reg=0;reg<4;reg++){
        int idx = (q*4+reg)*132 + dim;
        zb[idx] = zb[idx] + acc2o[t][reg] + bv;
      }
    }
    __syncthreads();
  }
  int md = *modep;
  const long ZIS = (long)NNODES*128;
  #pragma unroll
  for(int i=0;i<2;i++){
    int flat = (i*256 + threadIdx.x)*4;
    int node = flat>>7, k = flat&127;
    float4 v = *(float4*)(zb + node*132 + k);
    int n = n0 + node;
    uint2 pv = make_uint2(packbf(v.x,v.y), packbf(v.z,v.w));
    *(uint2*)(zib + (size_t)n*128 + k) = pv;
    if(md==1){
      uint16_t* ob = (uint16_t*)outb;
      *(uint2*)(ob + ZIS + (long)n*256 + k) = pv;
    } else {
      float* ob = (float*)outb;
      *(float4*)(ob + ZIS + (long)n*256 + k) = v;
    }
  }
  {
    int node2 = threadIdx.x>>4, c = threadIdx.x&15;
    float vv[8];
    #pragma unroll
    for(int mt=0;mt<8;mt++) vv[mt] = zb[node2*132 + mt*16 + c];
    uint4 o = make_uint4(packbf(vv[0],vv[1]), packbf(vv[2],vv[3]),
                         packbf(vv[4],vv[5]), packbf(vv[6],vv[7]));
    *(uint4*)(zib2 + (size_t)(n0+node2)*128 + c*8) = o;
  }
}

// ---------------- layer-1 msg ----------------
// R8: phase A dsts loads -> ONE coalesced 64-edge window load + __shfl (was 8 scalar
// broadcast loads per 32-edge group). Cuts the dsts->zib2 2-hop gather chain to 1 hop
// plus a 2-cycle shuffle. Everything else unchanged from R7.
__global__ __launch_bounds__(1024, 2) void k_msg1f(const int* __restrict__ offs,
                                               const int* __restrict__ dsts,
                                               const uint16_t* __restrict__ gs,
                                               const uint16_t* __restrict__ zib,
                                               const uint16_t* __restrict__ zib2,
                                               const uint16_t* __restrict__ Bf,
                                               const float* __restrict__ bias,
                                               float* __restrict__ zacc){
  __shared__ __align__(16) uint16_t ldsA[2*64*64*8];   // 128 KB
  int w = threadIdx.x>>6, l = threadIdx.x&63;
  int n0 = blockIdx.x*32;
  int col = l&15, quad = l>>4;
  for(int i=0;i<2;i++){
    int m = w*2 + i;
    int n = n0 + m;
    int beg = offs[n], end = offs[n+1];
    floatx4 acc[8];
    #pragma unroll
    for(int t=0;t<8;t++) acc[t] = (floatx4){0.f,0.f,0.f,0.f};
    for(int w0=beg; w0<end; w0+=64){
      int pidx = w0 + l;
      int dall = (pidx < end) ? dsts[pidx] : 0;   // coalesced: 64 edges per wave
      #pragma unroll
      for(int h=0;h<2;h++){
        int p0 = w0 + h*32;
        if(p0 >= end) break;
        int dn[8];
        union { short8 s; uint16_t u[8]; } Bg;
        #pragma unroll
        for(int j=0;j<8;j++){
          int p = p0 + quad*8 + j;
          int pc = p < end ? p : beg;
          dn[j] = __shfl(dall, h*32 + quad*8 + j);
          uint16_t g = gs[(size_t)pc*16 + col];
          Bg.u[j] = (p < end) ? g : (uint16_t)0;
        }
        uint4 row[8];
        #pragma unroll
        for(int j=0;j<8;j++)
          row[j] = *(const uint4*)(zib2 + (size_t)dn[j]*128 + col*8);
        #pragma unroll
        for(int mt=0;mt<8;mt++){
          union { short8 s; uint32_t u32[4]; } Az;
          #pragma unroll
          for(int cp=0;cp<4;cp++){
            uint32_t a = ((const uint32_t*)&row[2*cp])[mt>>1];
            uint32_t b = ((const uint32_t*)&row[2*cp+1])[mt>>1];
            Az.u32[cp] = __builtin_amdgcn_perm(b, a, (mt&1) ? 0x07060302u : 0x05040100u);
          }
          acc[mt] = __builtin_amdgcn_mfma_f32_16x16x32_bf16(Az.s, Bg.s, acc[mt], 0,0,0);
        }
      }
    }
    uint16_t* tile = ldsA + (size_t)(m>>4)*32768;
    int mloc = m & 15;
    #pragma unroll
    for(int mt=0;mt<8;mt++){
      int K0 = col*128 + mt*16 + quad*4;
      int kk = K0>>5, qt = (K0>>3)&3, jt = K0&7;
      int slot = kk*64 + ((qt*16 + mloc) ^ (kk>>2));
      uint32_t lo = packbf(acc[mt][0], acc[mt][1]);
      uint32_t hi = packbf(acc[mt][2], acc[mt][3]);
      *(uint2*)(&tile[slot*8 + jt]) = make_uint2(lo, hi);
    }
  }
  __syncthreads();
  int nt1 = w & 7, half = w >> 3;
  floatx4 accA = (floatx4){0.f,0.f,0.f,0.f};
  floatx4 accB = (floatx4){0.f,0.f,0.f,0.f};
  const short8* Bp = (const short8*)Bf;
  int kb = half*32, ke = kb + 32;
  #pragma unroll 8
  for(int kk=kb;kk<ke;kk++){
    int ai = (kk*64 + (l^(kk>>2)))*8;
    short8 a0 = *(const short8*)(&ldsA[ai]);
    short8 a1 = *(const short8*)(&ldsA[32768 + ai]);
    short8 b1 = Bp[(size_t)(kk*8+nt1)*64 + l];
    accA = __builtin_amdgcn_mfma_f32_16x16x32_bf16(a0, b1, accA, 0,0,0);
    accB = __builtin_amdgcn_mfma_f32_16x16x32_bf16(a1, b1, accB, 0,0,0);
  }
  #pragma unroll
  for(int t=0;t<2;t++){
    int kk = 64 + half*2 + t;
    uint4 za0 = *(const uint4*)(zib + (size_t)(n0+col)*128 + (kk-64)*32 + quad*8);
    uint4 za1 = *(const uint4*)(zib + (size_t)(n0+16+col)*128 + (kk-64)*32 + quad*8);
    union { short8 s; uint4 u; } A0, A1; A0.u = za0; A1.u = za1;
    short8 b1 = Bp[(size_t)(kk*8+nt1)*64 + l];
    accA = __builtin_amdgcn_mfma_f32_16x16x32_bf16(A0.s, b1, accA, 0,0,0);
    accB = __builtin_amdgcn_mfma_f32_16x16x32_bf16(A1.s, b1, accB, 0,0,0);
  }
  __syncthreads();
  float* red = (float*)ldsA;
  if(half==1){
    *(floatx4*)(&red[(nt1*64 + l)*4])     = accA;
    *(floatx4*)(&red[((8+nt1)*64 + l)*4]) = accB;
  }
  __syncthreads();
  if(half==0){
    floatx4 o0 = *(const floatx4*)(&red[(nt1*64 + l)*4]);
    floatx4 o1 = *(const floatx4*)(&red[((8+nt1)*64 + l)*4]);
    int d1 = nt1*16 + col;
    float bv = bias[d1];
    #pragma unroll
    for(int reg=0;reg<4;reg++){
      int nodeA = n0 + quad*4 + reg;
      int nodeB = n0 + 16 + quad*4 + reg;
      zacc[(size_t)nodeA*128 + d1] = siluf(accA[reg] + o0[reg] + bv);
      zacc[(size_t)nodeB*128 + d1] = siluf(accB[reg] + o1[reg] + bv);
    }
  }
}

// ---------------- layer-1 standalone onsite (unchanged) ----------------
__global__ __launch_bounds__(256) void k_onsite1(const float* __restrict__ zin,
                                                 const uint16_t* __restrict__ Waf,
                                                 const float* __restrict__ ba,
                                                 const uint16_t* __restrict__ Wbf,
                                                 const float* __restrict__ bb,
                                                 void* __restrict__ outb,
                                                 const int* __restrict__ modep){
  __shared__ float zb[16*132];
  __shared__ float hb[16*132];
  int w = threadIdx.x>>6, l = threadIdx.x&63;
  int n0 = blockIdx.x*16;
  int md = *modep;
  #pragma unroll
  for(int i=0;i<2;i++){
    int flat = (i*256 + threadIdx.x)*4;
    int node = flat>>7, k = flat&127;
    *(float4*)(zb + node*132 + k) = *(const float4*)(zin + (size_t)(n0+node)*128 + k);
  }
  __syncthreads();
  int m = l&15, q = l>>4;
  for(int j=0;j<3;j++){
    const short8* Ba = (const short8*)Waf + (size_t)j*2048 + l;
    floatx4 acc[2];
    acc[0] = (floatx4){0.f,0.f,0.f,0.f};
    acc[1] = (floatx4){0.f,0.f,0.f,0.f};
    #pragma unroll
    for(int kk=0;kk<4;kk++){
      const float* zp = zb + m*132 + kk*32 + q*8;
      float4 a0 = *(const float4*)zp, a1 = *(const float4*)(zp+4);
      union { short8 s; uint32_t u[4]; } A;
      A.u[0]=packbf(a0.x,a0.y); A.u[1]=packbf(a0.z,a0.w);
      A.u[2]=packbf(a1.x,a1.y); A.u[3]=packbf(a1.z,a1.w);
      #pragma unroll
      for(int t=0;t<2;t++){
        short8 bfr = Ba[(size_t)(kk*8 + w*2+t)*64];
        acc[t] = __builtin_amdgcn_mfma_f32_16x16x32_bf16(A.s, bfr, acc[t], 0,0,0);
      }
    }
    #pragma unroll
    for(int t=0;t<2;t++){
      int dim = (w*2+t)*16 + m;
      float bv = ba[j*128+dim];
      #pragma unroll
      for(int reg=0;reg<4;reg++)
        hb[(q*4+reg)*132 + dim] = siluf(acc[t][reg] + bv);
    }
    __syncthreads();
    const short8* Bb = (const short8*)Wbf + (size_t)j*2048 + l;
    floatx4 acc2[2];
    acc2[0] = (floatx4){0.f,0.f,0.f,0.f};
    acc2[1] = (floatx4){0.f,0.f,0.f,0.f};
    #pragma unroll
    for(int kk=0;kk<4;kk++){
      const float* hp = hb + m*132 + kk*32 + q*8;
      float4 a0 = *(const float4*)hp, a1 = *(const float4*)(hp+4);
      union { short8 s; uint32_t u[4]; } A;
      A.u[0]=packbf(a0.x,a0.y); A.u[1]=packbf(a0.z,a0.w);
      A.u[2]=packbf(a1.x,a1.y); A.u[3]=packbf(a1.z,a1.w);
      #pragma unroll
      for(int t=0;t<2;t++){
        short8 bfr = Bb[(size_t)(kk*8 + w*2+t)*64];
        acc2[t] = __builtin_amdgcn_mfma_f32_16x16x32_bf16(A.s, bfr, acc2[t], 0,0,0);
      }
    }
    #pragma unroll
    for(int t=0;t<2;t++){
      int dim = (w*2+t)*16 + m;
      float bv = bb[j*128+dim];
      #pragma unroll
      for(int reg=0;reg<4;reg++){
        int idx = (q*4+reg)*132 + dim;
        zb[idx] = zb[idx] + acc2[t][reg] + bv;
      }
    }
    __syncthreads();
  }
  const long ZIS = (long)NNODES*128;
  #pragma unroll
  for(int i=0;i<2;i++){
    int flat = (i*256 + threadIdx.x)*4;
    int node = flat>>7, k = flat&127;
    float4 v = *(float4*)(zb + node*132 + k);
    int n = n0 + node;
    if(md==1){
      uint2 pv = make_uint2(packbf(v.x,v.y), packbf(v.z,v.w));
      uint16_t* ob = (uint16_t*)outb;
      *(uint2*)(ob + ZIS + 128 + (long)n*256 + k) = pv;
      *(uint2*)(ob + (long)n*128 + k) = pv;
    } else {
      float* ob = (float*)outb;
      *(float4*)(ob + ZIS + 128 + (long)n*256 + k) = v;
      *(float4*)(ob + (long)n*128 + k) = v;
    }
  }
}

extern "C" void kernel_launch(void* const* d_in, const int* in_sizes, int n_in,
                              void* d_out, int out_size, void* d_ws, size_t ws_size,
                              hipStream_t stream){
  const int* species = (const int*)d_in[0];
  const int* esrc    = (const int*)d_in[1];
  const int* edst    = (const int*)d_in[2];
  const void* dist   = d_in[3];
  const void* swit   = d_in[4];
  const void* Z      = d_in[5];
  const void* Ws0    = d_in[6];
  const void* bs0    = d_in[7];
  const void* V0     = d_in[8];
  const void* Ws1    = d_in[9];
  const void* bs1    = d_in[10];
  const void* V1     = d_in[11];
  const void* Wa     = d_in[12];
  const void* ba     = d_in[13];
  const void* Wb     = d_in[14];
  const void* bb     = d_in[15];

  char* ws = (char*)d_ws;
  size_t off = 0;
  auto alloc = [&](size_t bytes)->void*{ void* p = ws + off; off = (off + bytes + 255) & ~(size_t)255; return p; };
  int*      offs = (int*)     alloc((size_t)(NNODES+1)*4);
  int*      cur  = (int*)     alloc((size_t)NNODES*4);
  int*      dsts = (int*)     alloc((size_t)NEDGES*4);
  int*      sps  = (int*)     alloc((size_t)NEDGES*4);
  uint16_t* gs   = (uint16_t*)alloc((size_t)NEDGES*16*2);      // 12.8 MB
  float*    zacc = (float*)   alloc((size_t)NNODES*128*4);     // 10.24 MB
  uint16_t* zib  = (uint16_t*)alloc((size_t)NNODES*128*2);     // 5.12 MB
  uint16_t* zib2 = (uint16_t*)alloc((size_t)NNODES*128*2);     // 5.12 MB (transposed)
  float*    ZWs0 = (float*)   alloc((size_t)51*128*4);
  uint16_t* zfb  = (uint16_t*)alloc((size_t)51*16*2);
  float*    biasb= (float*)   alloc((size_t)1664*4);           // ba(768) bb(768) bs1(128)
  uint16_t* Bf0  = (uint16_t*)alloc((size_t)8*8*64*8*2);       // 64 KB
  uint16_t* Bf1  = (uint16_t*)alloc((size_t)KS1*8*64*8*2);     // 557 KB
  uint16_t* Wfr  = (uint16_t*)alloc((size_t)12*16384*2);       // 384 KB
  int*      mode = (int*)     alloc(256);

  const int EB = (NEDGES+255)/256;
  hipMemsetAsync(cur, 0, NNODES*4, stream);

  // ONE prep launch (probe + hist + all weight prep + biases)
  k_prep<<<B_PREP,256,0,stream>>>(esrc, cur, dist, V0, Ws1, V1, Wa, Wb,
                                  Z, Ws0, bs0, ba, bb, bs1,
                                  Bf0, Bf1, Wfr, ZWs0, zfb, biasb, mode);
  k_scan <<<1,1024,0,stream>>>(cur, offs);
  k_fillG<<<EB,256,0,stream>>>(esrc, edst, species, cur, dist, swit, mode, dsts, sps, gs);

  uint16_t* WaF0 = Wfr;
  uint16_t* WaF1 = Wfr + (size_t)3*16384;
  uint16_t* WbF0 = Wfr + (size_t)6*16384;
  uint16_t* WbF1 = Wfr + (size_t)9*16384;
  float* BA0 = biasb;            // layer0 onsite-a biases (384)
  float* BA1 = biasb + 384;      // layer1
  float* BB0 = biasb + 768;      // layer0 onsite-b biases
  float* BB1 = biasb + 768 + 384;
  float* BS1 = biasb + 1536;     // layer1 zself bias (128)

  // layer 0 fused (msg + onsite) -> d_out stack[0], zib, zib2
  k_l0<<<MTILES,256,0,stream>>>(offs, sps, gs, zfb, Bf0, species, ZWs0,
                                WaF0, BA0, WbF0, BB0,
                                d_out, mode, zib, zib2);

  // layer 1: msg (split) -> zacc, then standalone onsite -> d_out final + stack[1]
  k_msg1f<<<MT2,1024,0,stream>>>(offs, dsts, gs, zib, zib2, Bf1, BS1, zacc);
  k_onsite1<<<MTILES,256,0,stream>>>(zacc, WaF1, BA1, WbF1, BB1,
                                     d_out, mode);
}